// Round 15
// baseline (274.638 us; speedup 1.0000x reference)
//
#include <hip/hip_runtime.h>
#include <math.h>

typedef unsigned long long u64;
typedef unsigned int u32;
typedef unsigned short u16;
typedef unsigned char u8;

#define VOL 1048576              // 64*128*128
#define NTOT 2097152             // 2 batches
#define NWORDS 32768             // NTOT/64
#define PC0 2048
#define PC1 2048

union HU { u16 u; _Float16 h; };
__device__ __forceinline__ float h2f(u16 u){ HU x; x.u=u; return (float)x.h; }
__device__ __forceinline__ u16 f2h(float f){ HU x; x.h=(_Float16)f; return x.u; }
#define H_ONE2 0x3C003C00u   // pair of 1.0 (erode-neutral)

__device__ __forceinline__ u32 pmin(u32 a, u32 b){ u32 r; asm("v_pk_min_f16 %0, %1, %2" : "=v"(r) : "v"(a), "v"(b)); return r; }
__device__ __forceinline__ u32 pmax(u32 a, u32 b){ u32 r; asm("v_pk_max_f16 %0, %1, %2" : "=v"(r) : "v"(a), "v"(b)); return r; }

__device__ __forceinline__ double wred(double v){
  #pragma unroll
  for(int o=32;o;o>>=1) v += __shfl_down(v, o);
  return v;
}

__device__ __forceinline__ u32 nib_compact(u64 v){
  v &= 0x0F0F0F0F0F0F0F0Full;
  v |= v>>4;  v &= 0x00FF00FF00FF00FFull;
  v |= v>>8;  v &= 0x0000FFFF0000FFFFull;
  v |= v>>16;
  return (u32)v;
}

// x-EDT for one voxel from its row's two bitwords
__device__ __forceinline__ int edt_x1(u64 w0, u64 w1, int x){
  int a = x-31;
  u64 win;
  if (a<0)        win = w0 << (-a);
  else if (a==0)  win = w0;
  else if (a<64)  win = (w0>>a)|(w1<<(64-a));
  else            win = w1>>(a-64);
  if (x<31) win |= (1ull<<(31-x))-1;
  if (x>95) win |= (~0ull)<<(159-x);
  u64 inv = ~win;
  u64 tl = inv & 0xFFFFFFFFull;
  u64 tr = inv>>31;
  int dl = tl ? (31-(63-__clzll(tl))) : 99;
  int dr = tr ? (__ffsll((unsigned long long)tr)-1) : 99;
  return min(min(dl,dr),16);
}

// ---------------- init: prob(fp16 x2), bitmasks, fused x-EDT, sums (float partials) --------
__global__ __launch_bounds__(256) void k_init(const float* __restrict__ net, const int* __restrict__ tgt,
    u16* __restrict__ img, u16* __restrict__ prob, u64* __restrict__ ybits, u64* __restrict__ hbits,
    u64* __restrict__ bimg2, u8* __restrict__ dA, double* __restrict__ part)
{
  __shared__ u64 nyb[32], nhb[32];
  __shared__ u64 swy[16], swh[16];
  __shared__ double sw[5][4];
  int tid = threadIdx.x;
  int r = blockIdx.x*256 + tid;
  int n0 = r<<2;
  int b = n0>>20, v0 = n0&(VOL-1);
  const float* nb = net + (size_t)b*(2*VOL);
  float4 a0 = *(const float4*)&nb[v0];
  float4 a1 = *(const float4*)&nb[VOL+v0];
  int4  tv = *(const int4*)&tgt[n0];
  float x0a[4] = {a0.x,a0.y,a0.z,a0.w};
  float x1a[4] = {a1.x,a1.y,a1.z,a1.w};
  int   ta[4]  = {tv.x,tv.y,tv.z,tv.w};
  float ce=0,tp=0,spr=0,sy=0,conn=0;
  u32 pk[2] = {0,0};
  u32 y4=0, h4=0;
  #pragma unroll
  for(int e=0;e<4;e++){
    float d = x1a[e]-x0a[e];
    int yb = (ta[e]>0) ? 1 : 0;
    float p = 1.f/(1.f+__expf(-d));
    y4 |= (u32)yb<<e;
    h4 |= (u32)(d>0.f)<<e;
    pk[e>>1] |= (u32)f2h(p) << ((e&1)*16);
    ce += log1pf(__expf(-fabsf(d))) + fmaxf(yb? -d : d, 0.f);
    tp += p*(float)yb;
    spr += p;
    sy += (float)yb;
    conn += (float)((int)((x0a[e]>0.5f)!=(yb!=0)) + (int)((x1a[e]>0.5f)!=(yb!=0)));
  }
  u32* f1 = (u32*)img;
  u32* f4 = (u32*)prob;
  int pi = r<<1;
  f1[pi] = pk[0]; f1[pi+1] = pk[1];
  f4[pi] = pk[0]; f4[pi+1] = pk[1];
  ((u8*)nyb)[tid] = (u8)y4;
  ((u8*)nhb)[tid] = (u8)h4;
  __syncthreads();
  if (tid < 16){
    u64 wy = (u64)nib_compact(nyb[tid*2]) | ((u64)nib_compact(nyb[tid*2+1])<<32);
    u64 wh = (u64)nib_compact(nhb[tid*2]) | ((u64)nib_compact(nhb[tid*2+1])<<32);
    int wi = blockIdx.x*16 + tid;
    ybits[wi]=wy; bimg2[wi]=wy;
    hbits[wi]=wh; bimg2[NWORDS+wi]=wh;
    swy[tid]=wy; swh[tid]=wh;
  }
  __syncthreads();
  {
    int ln = tid<<2;
    int row = ln>>7;
    int xq = ln&127;
    int gn0 = blockIdx.x*1024 + ln;
    u64 wy0 = swy[row*2], wy1 = swy[row*2+1];
    u64 wh0 = swh[row*2], wh1 = swh[row*2+1];
    u32 oy4=0, oh4=0;
    #pragma unroll
    for(int e=0;e<4;e++){
      oy4 |= (u32)edt_x1(wy0,wy1,xq+e) << (8*e);
      oh4 |= (u32)edt_x1(wh0,wh1,xq+e) << (8*e);
    }
    *(u32*)&dA[gn0] = oy4;
    *(u32*)&dA[(size_t)NTOT+gn0] = oh4;
  }
  int wid = tid>>6, lane = tid&63;
  double vals[5] = {(double)ce,(double)tp,(double)spr,(double)sy,(double)conn};
  #pragma unroll
  for(int s=0;s<5;s++){ double rr = wred(vals[s]); if(lane==0) sw[s][wid]=rr; }
  __syncthreads();
  if(tid==0){
    #pragma unroll
    for(int s=0;s<5;s++) part[(size_t)s*PC0 + blockIdx.x] = sw[s][0]+sw[s][1]+sw[s][2]+sw[s][3];
  }
}

// ---------------- binary morphology helpers ----------------
__device__ __forceinline__ u64 berode_x(const u64* P, int t){
  u64 c = P[t];
  if (t & 1) return c & ((c<<1)|(P[t-1]>>63)) & ((c>>1)|(1ull<<63));
  else       return c & ((c<<1)|1ull) & ((c>>1)|(P[t+1]<<63));
}
__device__ __forceinline__ u64 bdilate_x(const u64* P, int t){
  u64 c = P[t];
  if (t & 1) return c | (c<<1) | (P[t-1]>>63) | (c>>1);
  else       return c | (c<<1) | (c>>1) | (P[t+1]<<63);
}

// standalone bskel (256 threads) — first 5 iterations
template<bool INIT>
__global__ __launch_bounds__(256) void bskel(const u64* __restrict__ imgin, u64* __restrict__ imgout,
                                             u64* __restrict__ skel)
{
  __shared__ u64 simg[4][256];
  __shared__ u64 se1[6][256];
  __shared__ u64 se2[2][256];
  __shared__ u64 sM[4][256];
  int bid = blockIdx.x;
  int tzb = bid & 31, b = (bid>>5)&1, m = bid>>6;
  int z0 = tzb*2, z1 = z0+2;
  size_t base = (size_t)m*NWORDS + (size_t)b*16384;
  const u64* vin = imgin + base;
  u64* vout = imgout + base;
  u64* skl = skel + base;
  int tid = threadIdx.x;
  int y = tid>>1;

  for (int s = z0-3; s <= z1+6; ++s){
    if (s <= z1+2)
      simg[(s+96)&3][tid] = ((unsigned)s<64u) ? vin[(s<<8)+tid] : ~0ull;
    { int t = s-2;
      if (t >= z0-2 && t <= z1+1){
        u64 r = ~0ull;
        if ((unsigned)t<64u){
          const u64* P = simg[(t+96)&3];
          if (INIT) r = P[tid];
          else {
            r = berode_x(P, tid);
            if(y>0)   r &= P[tid-2];
            if(y<127) r &= P[tid+2];
            r &= simg[(t-1+96)&3][tid] & simg[(t+1+96)&3][tid];
          }
        }
        se1[(t+96)%6][tid] = r;
      }
    }
    { int t = s-4;
      if (t >= z0-1 && t <= z1){
        u64 r = 0;
        if ((unsigned)t<64u){
          const u64* P = se1[(t+96)%6];
          r = berode_x(P, tid);
          if(y>0)   r &= P[tid-2];
          if(y<127) r &= P[tid+2];
          r &= se1[(t-1+96)%6][tid] & se1[(t+1+96)%6][tid];
        }
        se2[(t+96)&1][tid] = r;
      }
    }
    { int t = s-5;
      if (t >= z0-1 && t <= z1){
        const u64* P = se2[(t+96)&1];
        u64 dm = bdilate_x(P, tid);
        if(y>0)   dm |= bdilate_x(P, tid-2);
        if(y<127) dm |= bdilate_x(P, tid+2);
        sM[(t+96)&3][tid] = dm;
      }
    }
    { int z = s-7;
      if (z >= z0 && z < z1){
        u64 open_ = sM[(z-1+96)&3][tid] | sM[(z+96)&3][tid] | sM[(z+1+96)&3][tid];
        u64 e1v = se1[(z+96)%6][tid];
        u64 d = e1v & ~open_;
        int gw = (z<<8)+tid;
        if (INIT) skl[gw] = d;
        else { skl[gw] |= d; vout[gw] = e1v; }
      }
    }
    __syncthreads();
  }
}

// ---------------- combined: one bskel iter (blocks 0..127) + fskel tile (128..1151) --------
// MODE 0: fskel2 INIT; 1: fskel2; 2: fskel1 (last d-term).
template<int MODE>
__global__ __launch_bounds__(512) void fsk_b(
    const u16* __restrict__ imgin, u16* __restrict__ imgout, u16* __restrict__ skel,
    const u64* __restrict__ bin, u64* __restrict__ bout, u64* __restrict__ bskl)
{
  __shared__ __align__(16) char smem_[33280];
  int bid = blockIdx.x;
  int tid = threadIdx.x;
  if (bid >= 128){
    int fb = bid - 128;
    int xb = fb&3, yb=(fb>>2)&15, zb=(fb>>6)&7, b=fb>>9;
    int X0=xb*32, Y0=yb*8, Z0=zb*8;
    const u32* vin = (const u32*)(imgin + (size_t)b*VOL);
    u32* skl = (u32*)(skel + (size_t)b*VOL);
    if (MODE < 2){
      u32* A_ = (u32*)smem_;        // 3920
      u32* B_ = A_ + 3920;          // 2592
      u32* C_ = B_ + 2592;          // 1800
      u32* vout = (u32*)(imgout + (size_t)b*VOL);
      // P0: load A, OOB -> 1.0
      for (int idx=tid; idx<3920; idx+=512){
        int z = idx/280; int rem = idx - z*280; int y = rem/20; int px = rem - y*20;
        int gz = Z0-3+z, gy = Y0-3+y, gx = X0-4+2*px;
        bool ok = ((unsigned)gz<64u) & ((unsigned)gy<128u) & ((unsigned)gx<128u);
        A_[idx] = ok ? vin[(gz<<13)+(gy<<6)+(gx>>1)] : H_ONE2;
      }
      __syncthreads();
      // P1: B = erode7(A), OOB word -> 1.0
      for (int idx=tid; idx<2592; idx+=512){
        int z = idx/216; int rem = idx - z*216; int y = rem/18; int px = rem - y*18;
        int gz = Z0-2+z, gy = Y0-2+y;
        bool zok = (unsigned)gz<64u, yok = (unsigned)gy<128u;
        bool xout = ((X0==0)&&(px==0)) || ((X0==96)&&(px==17));
        u32 v = H_ONE2;
        if (zok && yok && !xout){
          int c = (z+1)*280 + (y+1)*20 + (px+1);
          u32 C0=A_[c], L=A_[c-1], R=A_[c+1];
          u32 SL=(L>>16)|(C0<<16), SR=(C0>>16)|(R<<16);
          u32 m = pmin(pmin(SL,SR), C0);
          m = pmin(m, pmin(A_[c-20],A_[c+20]));
          v = pmin(m, pmin(A_[c-280],A_[c+280]));
        }
        B_[idx] = v;
      }
      __syncthreads();
      // P2: C = erode7(B), OOB word -> 0; write E_{k+2} center to global
      for (int idx=tid; idx<1800; idx+=512){
        int z = idx/180; int rem = idx - z*180; int y = rem/18; int px = rem - y*18;
        int gz = Z0-1+z, gy = Y0-1+y;
        bool zok=(unsigned)gz<64u, yok=(unsigned)gy<128u;
        bool xout = ((X0==0)&&(px==0)) || ((X0==96)&&(px==17));
        int pxm = (px>0)?px-1:0, pxp=(px<17)?px+1:17;
        u32 v = 0;
        if (zok && yok && !xout){
          int c = (z+1)*216 + (y+1)*18;
          u32 C0=B_[c+px], L=B_[c+pxm], R=B_[c+pxp];
          u32 SL=(L>>16)|(C0<<16), SR=(C0>>16)|(R<<16);
          u32 m = pmin(pmin(SL,SR), C0);
          m = pmin(m, pmin(B_[c+px-18],B_[c+px+18]));
          v = pmin(m, pmin(B_[c-216+px],B_[c+216+px]));
        }
        C_[idx] = v;
        if (px>=1 && px<=16 && y>=1 && y<=8 && z>=1 && z<=8)
          vout[(gz<<13)+(gy<<6)+((X0-2+2*px)>>1)] = v;
      }
      int zq = tid>>7, cc = tid&127;
      int oy = cc>>4, opx = cc&15;
      u32 ek0[2], ek1[2];
      #pragma unroll
      for(int j=0;j<2;j++){
        int z = zq*2+j;
        ek0[j] = A_[(z+3)*280 + (oy+3)*20 + (opx+2)];
        ek1[j] = B_[(z+2)*216 + (oy+2)*18 + (opx+1)];
      }
      __syncthreads();
      // P3: X1 = xmax(B) (masked), X2 = xmax(C) -> A space
      u32* X1 = A_; u32* X2 = A_ + 1600;
      for (int idx=tid; idx<3200; idx+=512){
        int arr = (idx>=1600);
        int r2 = arr ? idx-1600 : idx;
        int z = r2/160; int rem = r2 - z*160; int y = rem>>4; int px = rem&15;
        u32 v;
        if (!arr){
          int gz = Z0-1+z, gy = Y0-1+y;
          bool ok = ((unsigned)gz<64u) && ((unsigned)gy<128u);
          int c = (z+1)*216 + (y+1)*18 + (px+1);
          u32 C0=B_[c], L=B_[c-1], R=B_[c+1];
          if ((X0==0)&&(px==0)) L=0;
          if ((X0==96)&&(px==15)) R=0;
          u32 SL=(L>>16)|(C0<<16), SR=(C0>>16)|(R<<16);
          v = pmax(pmax(SL,SR), C0);
          if (!ok) v = 0;
        } else {
          int c = z*180 + y*18 + (px+1);
          u32 C0=C_[c], L=C_[c-1], R=C_[c+1];
          u32 SL=(L>>16)|(C0<<16), SR=(C0>>16)|(R<<16);
          v = pmax(pmax(SL,SR), C0);
        }
        A_[idx] = v;
      }
      __syncthreads();
      // P4: Y = ymax(X) -> B space
      for (int idx=tid; idx<2560; idx+=512){
        int arr = (idx>=1280);
        int r2 = arr ? idx-1280 : idx;
        int z = r2>>7; int rem = r2&127; int y = rem>>4; int px = rem&15;
        const u32* Xs = arr ? X2 : X1;
        int c = z*160 + y*16 + px;
        B_[idx] = pmax(pmax(Xs[c], Xs[c+16]), Xs[c+32]);
      }
      __syncthreads();
      // P5: zmax + two skel updates
      u32* Y1 = B_; u32* Y2 = B_ + 1280;
      {
        int gx = X0 + 2*opx;
        #pragma unroll
        for(int j=0;j<2;j++){
          int z = zq*2+j;
          int gz = Z0+z;
          int c = z*128 + oy*16 + opx;
          u32 o1 = pmax(pmax(Y1[c], Y1[c+128]), Y1[c+256]);
          u32 o2 = pmax(pmax(Y2[c], Y2[c+128]), Y2[c+256]);
          u32 idx = (u32)((gz<<13) + ((Y0+oy)<<6) + (gx>>1));
          float d0l = fmaxf(h2f((u16)ek0[j]) - h2f((u16)o1), 0.f);
          float d0h = fmaxf(h2f((u16)(ek0[j]>>16)) - h2f((u16)(o1>>16)), 0.f);
          float d1l = fmaxf(h2f((u16)ek1[j]) - h2f((u16)o2), 0.f);
          float d1h = fmaxf(h2f((u16)(ek1[j]>>16)) - h2f((u16)(o2>>16)), 0.f);
          float sl_, sh_;
          if (MODE==0){ sl_ = d0l; sh_ = d0h; }
          else {
            u32 swv = skl[idx];
            sl_ = h2f((u16)swv); sh_ = h2f((u16)(swv>>16));
            sl_ += fmaxf(d0l - sl_*d0l, 0.f); sh_ += fmaxf(d0h - sh_*d0h, 0.f);
          }
          sl_ += fmaxf(d1l - sl_*d1l, 0.f); sh_ += fmaxf(d1h - sh_*d1h, 0.f);
          skl[idx] = (u32)f2h(sl_) | ((u32)f2h(sh_)<<16);
        }
      }
    } else {
      // fskel1 body
      u32* A2 = (u32*)smem_;        // 2880
      u32* B2 = A2 + 2880;          // 1800
      for (int idx=tid; idx<2880; idx+=512){
        int z = idx/240; int rem = idx - z*240; int y = rem/20; int px = rem - y*20;
        int gz = Z0-2+z, gy = Y0-2+y, gx = X0-4+2*px;
        bool ok = ((unsigned)gz<64u) & ((unsigned)gy<128u) & ((unsigned)gx<128u);
        A2[idx] = ok ? vin[(gz<<13)+(gy<<6)+(gx>>1)] : H_ONE2;
      }
      __syncthreads();
      for (int idx=tid; idx<1800; idx+=512){
        int z = idx/180; int rem = idx - z*180; int y = rem/18; int px = rem - y*18;
        int gz = Z0-1+z, gy = Y0-1+y;
        bool zok=(unsigned)gz<64u, yok=(unsigned)gy<128u;
        bool xout = ((X0==0)&&(px==0)) || ((X0==96)&&(px==17));
        int pxm = (px>0)?px-1:0, pxp=(px<17)?px+1:17;
        u32 v = 0;
        if (zok && yok && !xout){
          int c = (z+1)*240 + (y+1)*20;
          u32 C0=A2[c+px+1], L=A2[c+pxm+1], R=A2[c+pxp+1];
          u32 SL=(L>>16)|(C0<<16), SR=(C0>>16)|(R<<16);
          u32 m = pmin(pmin(SL,SR), C0);
          m = pmin(m, pmin(A2[c+px+1-20],A2[c+px+1+20]));
          v = pmin(m, pmin(A2[c-240+px+1],A2[c+240+px+1]));
        }
        B2[idx] = v;
      }
      int zq = tid>>7, cc = tid&127;
      int oy = cc>>4, opx = cc&15;
      u32 ek[2];
      #pragma unroll
      for(int j=0;j<2;j++){
        int z = zq*2+j;
        ek[j] = A2[(z+2)*240 + (oy+2)*20 + (opx+2)];
      }
      __syncthreads();
      u32* X = A2;
      for (int idx=tid; idx<1600; idx+=512){
        int z = idx/160; int rem = idx - z*160; int y = rem>>4; int px = rem&15;
        int c = z*180 + y*18 + (px+1);
        u32 C0=B2[c], L=B2[c-1], R=B2[c+1];
        u32 SL=(L>>16)|(C0<<16), SR=(C0>>16)|(R<<16);
        A2[idx] = pmax(pmax(SL,SR), C0);
      }
      __syncthreads();
      u32* Y = B2;
      for (int idx=tid; idx<1280; idx+=512){
        int z = idx>>7; int rem = idx&127; int y = rem>>4; int px = rem&15;
        int c = z*160 + y*16 + px;
        B2[idx] = pmax(pmax(X[c], X[c+16]), X[c+32]);
      }
      __syncthreads();
      {
        int gx = X0 + 2*opx;
        #pragma unroll
        for(int j=0;j<2;j++){
          int z = zq*2+j;
          int gz = Z0+z;
          int c = z*128 + oy*16 + opx;
          u32 o = pmax(pmax(Y[c], Y[c+128]), Y[c+256]);
          u32 idx = (u32)((gz<<13) + ((Y0+oy)<<6) + (gx>>1));
          float dl = fmaxf(h2f((u16)ek[j]) - h2f((u16)o), 0.f);
          float dh = fmaxf(h2f((u16)(ek[j]>>16)) - h2f((u16)(o>>16)), 0.f);
          u32 swv = skl[idx];
          float sl_ = h2f((u16)swv), sh_ = h2f((u16)(swv>>16));
          sl_ += fmaxf(dl - sl_*dl, 0.f); sh_ += fmaxf(dh - sh_*dh, 0.f);
          skl[idx] = (u32)f2h(sl_) | ((u32)f2h(sh_)<<16);
        }
      }
    }
  } else {
    // -------- one bskel<false> iteration, blocks 0..127 (scheduled first) --------
    u64* sim = (u64*)smem_;        // 4*256
    u64* se1 = sim + 1024;         // 6*256
    u64* se2 = se1 + 1536;         // 2*256
    u64* sM  = se2 + 512;          // 4*256
    int bid2 = bid;
    int tzb = bid2 & 31, b = (bid2>>5)&1, m = bid2>>6;
    int z0 = tzb*2, z1 = z0+2;
    size_t base = (size_t)m*NWORDS + (size_t)b*16384;
    const u64* vin = bin + base;
    u64* vout = bout + base;
    u64* skl = bskl + base;
    int y = tid>>1;
    for (int s = z0-3; s <= z1+6; ++s){
      if (tid < 256){
        if (s <= z1+2)
          sim[((s+96)&3)*256+tid] = ((unsigned)s<64u) ? vin[(s<<8)+tid] : ~0ull;
        { int t = s-2;
          if (t >= z0-2 && t <= z1+1){
            u64 r = ~0ull;
            if ((unsigned)t<64u){
              const u64* P = sim + ((t+96)&3)*256;
              r = berode_x(P, tid);
              if(y>0)   r &= P[tid-2];
              if(y<127) r &= P[tid+2];
              r &= sim[((t-1+96)&3)*256+tid] & sim[((t+1+96)&3)*256+tid];
            }
            se1[((t+96)%6)*256+tid] = r;
          }
        }
        { int t = s-4;
          if (t >= z0-1 && t <= z1){
            u64 r = 0;
            if ((unsigned)t<64u){
              const u64* P = se1 + ((t+96)%6)*256;
              r = berode_x(P, tid);
              if(y>0)   r &= P[tid-2];
              if(y<127) r &= P[tid+2];
              r &= se1[((t-1+96)%6)*256+tid] & se1[((t+1+96)%6)*256+tid];
            }
            se2[((t+96)&1)*256+tid] = r;
          }
        }
        { int t = s-5;
          if (t >= z0-1 && t <= z1){
            const u64* P = se2 + ((t+96)&1)*256;
            u64 dm = bdilate_x(P, tid);
            if(y>0)   dm |= bdilate_x(P, tid-2);
            if(y<127) dm |= bdilate_x(P, tid+2);
            sM[((t+96)&3)*256+tid] = dm;
          }
        }
        { int z = s-7;
          if (z >= z0 && z < z1){
            u64 open_ = sM[((z-1+96)&3)*256+tid] | sM[((z+96)&3)*256+tid] | sM[((z+1+96)&3)*256+tid];
            u64 e1v = se1[((z+96)%6)*256+tid];
            u64 d = e1v & ~open_;
            int gw = (z<<8)+tid;
            skl[gw] |= d;
            vout[gw] = e1v;
          }
        }
      }
      __syncthreads();
    }
  }
}

// ---------------- EDT y-pass (x-pass fused into k_init) ----------------
__global__ __launch_bounds__(256) void edt_py(const u8* __restrict__ din, u8* __restrict__ dout){
  int g = blockIdx.x*256 + threadIdx.x;
  int n = g & (NTOT-1);
  int c = (n >> 7) & 127;
  size_t idx = (size_t)g;
  int best = din[idx];
  #pragma unroll 4
  for (int k=1; k<=16; ++k){
    if (best <= k) break;
    int v = 255;
    if (c-k >= 0)   v = din[idx - (size_t)k*128];
    if (c+k < 128)  v = min(v, (int)din[idx + (size_t)k*128]);
    best = min(best, max(k, v));
  }
  dout[idx] = (u8)best;
}

// z-pass + per-block skeleton-radius max/min partials
__global__ __launch_bounds__(256) void edt_pz_part(const u8* __restrict__ din, u8* __restrict__ dout,
    const u64* __restrict__ skel2, const u64* __restrict__ hbits,
    u8* __restrict__ pmaxv, u8* __restrict__ pminv)
{
  int tid = threadIdx.x;
  int g = blockIdx.x*256 + tid;
  int m = g >> 21;
  int n = g & (NTOT-1);
  int c = (n >> 14) & 63;
  size_t idx = (size_t)g;
  int best = din[idx];
  #pragma unroll 4
  for (int k=1; k<=16; ++k){
    if (best <= k) break;
    int v = 255;
    if (c-k >= 0)  v = din[idx - (size_t)k*16384];
    if (c+k < 64)  v = min(v, (int)din[idx + (size_t)k*16384]);
    best = min(best, max(k, v));
  }
  dout[idx] = (u8)best;
  int wi = n>>6, bit = n&63;
  u64 sbit = m ? (skel2[NWORDS+wi] & hbits[wi]) : skel2[wi];
  u32 r = (u32)((sbit>>bit)&1ull) ? (u32)best : 0u;
  __shared__ u32 sx[256], sn_[256];
  sx[tid]=r; sn_[tid]=r;
  __syncthreads();
  for(int s=128;s>0;s>>=1){
    if(tid<s){
      if(sx[tid+s]>sx[tid]) sx[tid]=sx[tid+s];
      if(sn_[tid+s]<sn_[tid]) sn_[tid]=sn_[tid+s];
    }
    __syncthreads();
  }
  if(tid==0){ pmaxv[blockIdx.x]=(u8)sx[0]; pminv[blockIdx.x]=(u8)sn_[0]; }
}

// reduce 16384 block partials -> mm[8]
__global__ __launch_bounds__(256) void rmm2(const u8* __restrict__ pmaxv, const u8* __restrict__ pminv,
                                            u32* __restrict__ mm){
  __shared__ u8 smx[4][256], smn[4][256];
  int tid = threadIdx.x;
  u8 mx[4]={0,0,0,0}, mn[4]={255,255,255,255};
  for(int i=tid;i<16384;i+=256){
    int sel=i>>13, b=(i>>12)&1, cc=sel*2+b;
    u8 a=pmaxv[i], d=pminv[i];
    if(a>mx[cc]) mx[cc]=a;
    if(d<mn[cc]) mn[cc]=d;
  }
  #pragma unroll
  for(int cc=0;cc<4;cc++){ smx[cc][tid]=mx[cc]; smn[cc][tid]=mn[cc]; }
  __syncthreads();
  for(int s=128;s>0;s>>=1){
    if(tid<s){
      #pragma unroll
      for(int cc=0;cc<4;cc++){
        if(smx[cc][tid+s]>smx[cc][tid]) smx[cc][tid]=smx[cc][tid+s];
        if(smn[cc][tid+s]<smn[cc][tid]) smn[cc][tid]=smn[cc][tid+s];
      }
    }
    __syncthreads();
  }
  if(tid==0){
    #pragma unroll
    for(int cc=0;cc<4;cc++){
      int sel=cc>>1, b=cc&1;
      mm[sel*4+b]   = (u32)smx[cc][0];
      mm[sel*4+2+b] = (u32)smn[cc][0];
    }
  }
}

// ---------------- k_tail: LDS-tiled separable sobel + final reduce ----------------
// fp16 logit tile; target stencil terms from wrow bit-windows (no int LDS planes).
// LDS ~20.2 KB -> 8 blocks/CU.
__global__ __launch_bounds__(256) void k_tail(const float* __restrict__ net, const u16* __restrict__ prob,
    const u16* __restrict__ skelp, const u64* __restrict__ ybits, const u64* __restrict__ hbits,
    const u64* __restrict__ skel2, const u8* __restrict__ acc, const u32* __restrict__ mm,
    double* __restrict__ part1)
{
  __shared__ u16  lp[2040];      // [6][10][34] logits ch0 (fp16), zero-padded
  __shared__ float dxp[1920];    // [6][10][32] x-deriv
  __shared__ float sxp[1920];    // [6][10][32] x-smooth
  __shared__ u64   wrow[60];     // [6][10] target bit windows (bit i <-> gx=X0-1+i)
  __shared__ double sw[9][4];
  int tid = threadIdx.x;
  int bid = blockIdx.x;
  int xb = bid&3, ybk=(bid>>2)&15, zbk=(bid>>6)&15, b=bid>>10;
  int X0=xb*32, Y0=ybk*8, Z0=zbk*4;
  const float* P = net + (size_t)b*(2*VOL);
  float rmaxT = fmaxf((float)mm[b],1.f),   rminT = fmaxf((float)mm[2+b],1.f);
  float rmaxH = fmaxf((float)mm[4+b],1.f), rminH = fmaxf((float)mm[6+b],1.f);
  for (int idx=tid; idx<2040; idx+=256){
    int zr = idx/340; int rem = idx-zr*340; int yr = rem/34; int xi = rem-yr*34;
    int gz=Z0-1+zr, gy=Y0-1+yr, gx=X0-1+xi;
    float v = 0.f;
    if((unsigned)gz<64u && (unsigned)gy<128u && (unsigned)gx<128u)
      v = P[(gz<<14)+(gy<<7)+gx];
    lp[idx] = f2h(v);
  }
  if (tid < 60){
    int zr = tid/10, yr = tid-zr*10;
    int gz=Z0-1+zr, gy=Y0-1+yr;
    u64 wn = 0;
    if((unsigned)gz<64u && (unsigned)gy<128u){
      const u64* yw = ybits + ((size_t)b<<14) + (gz<<8) + (gy<<1);
      u64 w0 = yw[0], w1 = yw[1];
      if (X0==0) wn = w0<<1;
      else { int s = X0-1; wn = (s<64) ? ((w0>>s)|(w1<<(64-s))) : (w1>>(s-64)); }
    }
    wrow[tid] = wn;
  }
  __syncthreads();
  for (int idx=tid; idx<1920; idx+=256){
    int zr = idx/320; int rem = idx-zr*320; int yr = rem>>5; int x = rem&31;
    int c = zr*340 + yr*34 + x;
    float l0=h2f(lp[c]), l1=h2f(lp[c+1]), l2=h2f(lp[c+2]);
    dxp[idx] = l2-l0;
    sxp[idx] = l0+2.f*l1+l2;
  }
  __syncthreads();
  int oy = tid>>5, ox = tid&31;
  float A1[6],A2[6],A3[6];
  int   B1v[6],B2v[6],B3v[6];
  #pragma unroll
  for(int zr=0; zr<6; ++zr){
    int base = zr*320 + oy*32 + ox;
    float d0=dxp[base], d1=dxp[base+32], d2=dxp[base+64];
    A1[zr] = d0+2.f*d1+d2;
    A2[zr] = d0+d1+d2;
    float s0=sxp[base], s1=sxp[base+32], s2=sxp[base+64];
    A3[zr] = s0+s1+s2;
    int a0=(int)((wrow[zr*10+oy  ]>>ox)&7ull);
    int a1=(int)((wrow[zr*10+oy+1]>>ox)&7ull);
    int a2=(int)((wrow[zr*10+oy+2]>>ox)&7ull);
    int t0=(a0>>2)-(a0&1), t1=(a1>>2)-(a1&1), t2=(a2>>2)-(a2&1);
    int u0=(a0&1)+2*((a0>>1)&1)+(a0>>2);
    int u1=(a1&1)+2*((a1>>1)&1)+(a1>>2);
    int u2=(a2&1)+2*((a2>>1)&1)+(a2>>2);
    B1v[zr] = t0+2*t1+t2;
    B2v[zr] = t0+t1+t2;
    B3v[zr] = u0+u1+u2;
  }
  float fsob=0,cl1=0,cl2=0,cl3=0,cl4=0,i1=0,un1=0,i2=0,un2=0;
  #pragma unroll
  for(int zc=0; zc<4; ++zc){
    float gpx = A1[zc]+A1[zc+1]+A1[zc+2];
    float gpy = A2[zc]+2.f*A2[zc+1]+A2[zc+2];
    float gpz = A3[zc+2]-A3[zc];
    float ftx = (float)(B1v[zc]+B1v[zc+1]+B1v[zc+2]);
    float fty = (float)(B2v[zc]+2*B2v[zc+1]+B2v[zc+2]);
    float ftz = (float)(B3v[zc+2]-B3v[zc]);
    float s1 = gpx*gpx+gpy*gpy+gpz*gpz;
    float s2 = ftx*ftx+fty*fty+ftz*ftz;
    if (s1>0.f && s2>0.f){
      float ip = rsqrtf(s1), it = rsqrtf(s2);
      fsob += (gpx*ftx+gpy*fty+gpz*ftz)*ip*it;
    }
    int gz=Z0+zc, gy=Y0+oy, gx=X0+ox;
    int n = (b<<20)+(gz<<14)+(gy<<7)+gx;
    int yb = (int)((wrow[(zc+1)*10+(oy+1)] >> (ox+1)) & 1ull);
    int wi = n>>6, bit = n&63;
    int hd = (int)((hbits[wi]>>bit)&1ull);
    int sT = (int)((skel2[wi]>>bit)&1ull);
    int sH = (int)((skel2[NWORDS+wi]>>bit)&1ull);
    float dT = (float)acc[n];
    float dH = (float)acc[(size_t)NTOT+n];
    float p  = h2f(prob[n]);
    float sk = h2f(skelp[n]);
    cl1 += sk*(float)yb;
    cl2 += sk;
    float q_vl = yb ? fminf(dT,rmaxT)/rmaxT : 0.f;
    if (sT){
      cl3 += p; cl4 += 1.f;
      float t=(rmaxT-dT+rminT)/rmaxT; float q_sl=t*t;
      float q_vp = fminf(dH,rmaxH)/rmaxH*p;
      i2  += q_sl*__powf(q_vp+1e-4f,0.7f)*q_sl;
      un2 += q_sl*(0.1f*q_vp+0.9f*q_sl);
    }
    if (sH & hd){
      float t=(rmaxH-dH+rminH)/rmaxH; float q_sp=t*t*p;
      i1  += q_sp*__powf(q_sp+1e-4f,0.7f)*q_vl;
      un1 += q_sp*(0.1f*q_sp+0.9f*q_vl);
    }
  }
  int wid = tid>>6, lane = tid&63;
  double vals[9] = {(double)fsob,(double)cl1,(double)cl2,(double)cl3,(double)cl4,
                    (double)i1,(double)un1,(double)i2,(double)un2};
  #pragma unroll
  for(int s=0;s<9;s++){ double rr = wred(vals[s]); if(lane==0) sw[s][wid]=rr; }
  __syncthreads();
  if(tid==0){
    #pragma unroll
    for(int s=0;s<9;s++) part1[(size_t)s*PC1 + bid] = sw[s][0]+sw[s][1]+sw[s][2]+sw[s][3];
  }
}

// ---------------- two-stage finalize ----------------
__global__ __launch_bounds__(256) void k_reduce_mid(const double* __restrict__ part0,
                                                    const double* __restrict__ part1,
                                                    double* __restrict__ tot){
  int s = blockIdx.x;
  const double* src; int n;
  if (s < 5){ src = part0 + (size_t)s*PC0; n = PC0; }
  else      { src = part1 + (size_t)(s-5)*PC1; n = PC1; }
  double v=0;
  for(int i=threadIdx.x;i<n;i+=256) v += src[i];
  __shared__ double sd[256];
  sd[threadIdx.x]=v; __syncthreads();
  for(int k=128;k>0;k>>=1){ if((int)threadIdx.x<k) sd[threadIdx.x]+=sd[threadIdx.x+k]; __syncthreads(); }
  if(threadIdx.x==0) tot[s]=sd[0];
}

__global__ void k_fin(const double* __restrict__ tot, float* __restrict__ out){
  if(threadIdx.x==0 && blockIdx.x==0){
    const double N = (double)NTOT;
    double ce = tot[0]/N;
    double tp=tot[1], fp=tot[2]-tot[1], fn=tot[3]-tot[1];
    double dice = -((2.0*tp+1e-5)/(2.0*tp+fp+fn+1e-5));
    double conn = tot[4]/(2.0*N);
    double dir  = 1.0 - tot[5]/N;
    double tprec = (tot[6]+1.0)/(tot[7]+1.0);
    double tsens = (tot[8]+1.0)/(tot[9]+1.0);
    double cld = 1.0 - 2.0*tprec*tsens/(tprec+tsens);
    double u1 = 1.0 - (tot[10]+1.0)/(tot[11]+1.0);
    double u2 = 1.0 - (tot[12]+1.0)/(tot[13]+1.0);
    out[0] = (float)(dice+ce+cld+dir+conn+u1+u2);
  }
}

extern "C" void kernel_launch(void* const* d_in, const int* in_sizes, int n_in,
                              void* d_out, int out_size, void* d_ws, size_t ws_size,
                              hipStream_t stream)
{
  (void)in_sizes; (void)n_in; (void)out_size; (void)ws_size;
  const float* net = (const float*)d_in[0];
  const int*   tgt = (const int*)d_in[1];
  float* out = (float*)d_out;
  char* w = (char*)d_ws;
  const size_t MB = 1024*1024;
  u16* F1 = (u16*)(w + 0*MB);              // prob img ping (fp16)
  u16* F2 = (u16*)(w + 4*MB);              // skel_pred
  u16* F3 = (u16*)(w + 8*MB);              // img pong
  u16* F4 = (u16*)(w + 12*MB);             // pristine prob copy
  u64* ybits = (u64*)(w + 16*MB);
  u64* hbits = ybits + NWORDS;
  u64* skel2 = hbits + NWORDS;
  u64* bping = skel2 + 2*NWORDS;
  u64* bpong = bping + 2*NWORDS;
  u8*  dA    = (u8*)(bpong + 2*NWORDS);
  u8*  dB    = dA + (size_t)2*NTOT;
  double* part0 = (double*)(dB + (size_t)2*NTOT);
  double* part1 = part0 + (size_t)5*PC0;
  double* tot   = part1 + (size_t)9*PC1;
  u8* pmaxv = (u8*)(tot + 16);
  u8* pminv = pmaxv + 16384;
  u32* mm  = (u32*)(pminv + 16384);

  k_init<<<PC0, 256, 0, stream>>>(net, tgt, F1, F4, ybits, hbits, bping, dA, part0);

  // binary skeleton: INIT + 4 false iterations standalone
  bskel<true><<<128,256,0,stream>>>(bping, bpong, skel2);
  bskel<false><<<128,256,0,stream>>>(bping, bpong, skel2);
  bskel<false><<<128,256,0,stream>>>(bpong, bping, skel2);
  bskel<false><<<128,256,0,stream>>>(bping, bpong, skel2);
  bskel<false><<<128,256,0,stream>>>(bpong, bping, skel2);

  // fskel chain (6 dispatches) with bskel false #5..#10 piggybacked (blocks 0..127)
  fsk_b<0><<<1152,512,0,stream>>>(F1, F3, F2, bping, bpong, skel2);
  fsk_b<1><<<1152,512,0,stream>>>(F3, F1, F2, bpong, bping, skel2);
  fsk_b<1><<<1152,512,0,stream>>>(F1, F3, F2, bping, bpong, skel2);
  fsk_b<1><<<1152,512,0,stream>>>(F3, F1, F2, bpong, bping, skel2);
  fsk_b<1><<<1152,512,0,stream>>>(F1, F3, F2, bping, bpong, skel2);
  fsk_b<2><<<1152,512,0,stream>>>(F3, F1, F2, bpong, bping, skel2);

  const int GE = (2*NTOT)/256;
  edt_py<<<GE,256,0,stream>>>(dA, dB);
  edt_pz_part<<<GE,256,0,stream>>>(dB, dA, skel2, hbits, pmaxv, pminv);
  rmm2<<<1,256,0,stream>>>(pmaxv, pminv, mm);

  k_tail<<<PC1,256,0,stream>>>(net, F4, F2, ybits, hbits, skel2, dA, mm, part1);
  k_reduce_mid<<<14,256,0,stream>>>(part0, part1, tot);
  k_fin<<<1,64,0,stream>>>(tot, out);
}

// Round 16
// 271.716 us; speedup vs baseline: 1.0108x; 1.0108x over previous
//
#include <hip/hip_runtime.h>
#include <math.h>

typedef unsigned long long u64;
typedef unsigned int u32;
typedef unsigned short u16;
typedef unsigned char u8;

#define VOL 1048576              // 64*128*128
#define NTOT 2097152             // 2 batches
#define NWORDS 32768             // NTOT/64
#define PC0 2048
#define PC1 2048

union HU { u16 u; _Float16 h; };
__device__ __forceinline__ float h2f(u16 u){ HU x; x.u=u; return (float)x.h; }
__device__ __forceinline__ u16 f2h(float f){ HU x; x.h=(_Float16)f; return x.u; }
#define H_ONE2 0x3C003C00u   // pair of 1.0 (erode-neutral)

__device__ __forceinline__ u32 pmin(u32 a, u32 b){ u32 r; asm("v_pk_min_f16 %0, %1, %2" : "=v"(r) : "v"(a), "v"(b)); return r; }
__device__ __forceinline__ u32 pmax(u32 a, u32 b){ u32 r; asm("v_pk_max_f16 %0, %1, %2" : "=v"(r) : "v"(a), "v"(b)); return r; }

__device__ __forceinline__ double wred(double v){
  #pragma unroll
  for(int o=32;o;o>>=1) v += __shfl_down(v, o);
  return v;
}

__device__ __forceinline__ u32 nib_compact(u64 v){
  v &= 0x0F0F0F0F0F0F0F0Full;
  v |= v>>4;  v &= 0x00FF00FF00FF00FFull;
  v |= v>>8;  v &= 0x0000FFFF0000FFFFull;
  v |= v>>16;
  return (u32)v;
}

// x-EDT for one voxel from its row's two bitwords
__device__ __forceinline__ int edt_x1(u64 w0, u64 w1, int x){
  int a = x-31;
  u64 win;
  if (a<0)        win = w0 << (-a);
  else if (a==0)  win = w0;
  else if (a<64)  win = (w0>>a)|(w1<<(64-a));
  else            win = w1>>(a-64);
  if (x<31) win |= (1ull<<(31-x))-1;
  if (x>95) win |= (~0ull)<<(159-x);
  u64 inv = ~win;
  u64 tl = inv & 0xFFFFFFFFull;
  u64 tr = inv>>31;
  int dl = tl ? (31-(63-__clzll(tl))) : 99;
  int dr = tr ? (__ffsll((unsigned long long)tr)-1) : 99;
  return min(min(dl,dr),16);
}

// ---------------- init: prob(fp16 x2), bitmasks, fused x-EDT, sums (float partials) --------
__global__ __launch_bounds__(256) void k_init(const float* __restrict__ net, const int* __restrict__ tgt,
    u16* __restrict__ img, u16* __restrict__ prob, u64* __restrict__ ybits, u64* __restrict__ hbits,
    u64* __restrict__ bimg2, u8* __restrict__ dA, double* __restrict__ part)
{
  __shared__ u64 nyb[32], nhb[32];
  __shared__ u64 swy[16], swh[16];
  __shared__ double sw[5][4];
  int tid = threadIdx.x;
  int r = blockIdx.x*256 + tid;
  int n0 = r<<2;
  int b = n0>>20, v0 = n0&(VOL-1);
  const float* nb = net + (size_t)b*(2*VOL);
  float4 a0 = *(const float4*)&nb[v0];
  float4 a1 = *(const float4*)&nb[VOL+v0];
  int4  tv = *(const int4*)&tgt[n0];
  float x0a[4] = {a0.x,a0.y,a0.z,a0.w};
  float x1a[4] = {a1.x,a1.y,a1.z,a1.w};
  int   ta[4]  = {tv.x,tv.y,tv.z,tv.w};
  float ce=0,tp=0,spr=0,sy=0,conn=0;
  u32 pk[2] = {0,0};
  u32 y4=0, h4=0;
  #pragma unroll
  for(int e=0;e<4;e++){
    float d = x1a[e]-x0a[e];
    int yb = (ta[e]>0) ? 1 : 0;
    float p = 1.f/(1.f+__expf(-d));
    y4 |= (u32)yb<<e;
    h4 |= (u32)(d>0.f)<<e;
    pk[e>>1] |= (u32)f2h(p) << ((e&1)*16);
    ce += log1pf(__expf(-fabsf(d))) + fmaxf(yb? -d : d, 0.f);
    tp += p*(float)yb;
    spr += p;
    sy += (float)yb;
    conn += (float)((int)((x0a[e]>0.5f)!=(yb!=0)) + (int)((x1a[e]>0.5f)!=(yb!=0)));
  }
  u32* f1 = (u32*)img;
  u32* f4 = (u32*)prob;
  int pi = r<<1;
  f1[pi] = pk[0]; f1[pi+1] = pk[1];
  f4[pi] = pk[0]; f4[pi+1] = pk[1];
  ((u8*)nyb)[tid] = (u8)y4;
  ((u8*)nhb)[tid] = (u8)h4;
  __syncthreads();
  if (tid < 16){
    u64 wy = (u64)nib_compact(nyb[tid*2]) | ((u64)nib_compact(nyb[tid*2+1])<<32);
    u64 wh = (u64)nib_compact(nhb[tid*2]) | ((u64)nib_compact(nhb[tid*2+1])<<32);
    int wi = blockIdx.x*16 + tid;
    ybits[wi]=wy; bimg2[wi]=wy;
    hbits[wi]=wh; bimg2[NWORDS+wi]=wh;
    swy[tid]=wy; swh[tid]=wh;
  }
  __syncthreads();
  {
    int ln = tid<<2;
    int row = ln>>7;
    int xq = ln&127;
    int gn0 = blockIdx.x*1024 + ln;
    u64 wy0 = swy[row*2], wy1 = swy[row*2+1];
    u64 wh0 = swh[row*2], wh1 = swh[row*2+1];
    u32 oy4=0, oh4=0;
    #pragma unroll
    for(int e=0;e<4;e++){
      oy4 |= (u32)edt_x1(wy0,wy1,xq+e) << (8*e);
      oh4 |= (u32)edt_x1(wh0,wh1,xq+e) << (8*e);
    }
    *(u32*)&dA[gn0] = oy4;
    *(u32*)&dA[(size_t)NTOT+gn0] = oh4;
  }
  int wid = tid>>6, lane = tid&63;
  double vals[5] = {(double)ce,(double)tp,(double)spr,(double)sy,(double)conn};
  #pragma unroll
  for(int s=0;s<5;s++){ double rr = wred(vals[s]); if(lane==0) sw[s][wid]=rr; }
  __syncthreads();
  if(tid==0){
    #pragma unroll
    for(int s=0;s<5;s++) part[(size_t)s*PC0 + blockIdx.x] = sw[s][0]+sw[s][1]+sw[s][2]+sw[s][3];
  }
}

// ---------------- binary morphology helpers ----------------
__device__ __forceinline__ u64 berode_x(const u64* P, int t){
  u64 c = P[t];
  if (t & 1) return c & ((c<<1)|(P[t-1]>>63)) & ((c>>1)|(1ull<<63));
  else       return c & ((c<<1)|1ull) & ((c>>1)|(P[t+1]<<63));
}
__device__ __forceinline__ u64 bdilate_x(const u64* P, int t){
  u64 c = P[t];
  if (t & 1) return c | (c<<1) | (P[t-1]>>63) | (c>>1);
  else       return c | (c<<1) | (c>>1) | (P[t+1]<<63);
}

// standalone bskel (256 threads) — first 5 iterations
template<bool INIT>
__global__ __launch_bounds__(256) void bskel(const u64* __restrict__ imgin, u64* __restrict__ imgout,
                                             u64* __restrict__ skel)
{
  __shared__ u64 simg[4][256];
  __shared__ u64 se1[6][256];
  __shared__ u64 se2[2][256];
  __shared__ u64 sM[4][256];
  int bid = blockIdx.x;
  int tzb = bid & 31, b = (bid>>5)&1, m = bid>>6;
  int z0 = tzb*2, z1 = z0+2;
  size_t base = (size_t)m*NWORDS + (size_t)b*16384;
  const u64* vin = imgin + base;
  u64* vout = imgout + base;
  u64* skl = skel + base;
  int tid = threadIdx.x;
  int y = tid>>1;

  for (int s = z0-3; s <= z1+6; ++s){
    if (s <= z1+2)
      simg[(s+96)&3][tid] = ((unsigned)s<64u) ? vin[(s<<8)+tid] : ~0ull;
    { int t = s-2;
      if (t >= z0-2 && t <= z1+1){
        u64 r = ~0ull;
        if ((unsigned)t<64u){
          const u64* P = simg[(t+96)&3];
          if (INIT) r = P[tid];
          else {
            r = berode_x(P, tid);
            if(y>0)   r &= P[tid-2];
            if(y<127) r &= P[tid+2];
            r &= simg[(t-1+96)&3][tid] & simg[(t+1+96)&3][tid];
          }
        }
        se1[(t+96)%6][tid] = r;
      }
    }
    { int t = s-4;
      if (t >= z0-1 && t <= z1){
        u64 r = 0;
        if ((unsigned)t<64u){
          const u64* P = se1[(t+96)%6];
          r = berode_x(P, tid);
          if(y>0)   r &= P[tid-2];
          if(y<127) r &= P[tid+2];
          r &= se1[(t-1+96)%6][tid] & se1[(t+1+96)%6][tid];
        }
        se2[(t+96)&1][tid] = r;
      }
    }
    { int t = s-5;
      if (t >= z0-1 && t <= z1){
        const u64* P = se2[(t+96)&1];
        u64 dm = bdilate_x(P, tid);
        if(y>0)   dm |= bdilate_x(P, tid-2);
        if(y<127) dm |= bdilate_x(P, tid+2);
        sM[(t+96)&3][tid] = dm;
      }
    }
    { int z = s-7;
      if (z >= z0 && z < z1){
        u64 open_ = sM[(z-1+96)&3][tid] | sM[(z+96)&3][tid] | sM[(z+1+96)&3][tid];
        u64 e1v = se1[(z+96)%6][tid];
        u64 d = e1v & ~open_;
        int gw = (z<<8)+tid;
        if (INIT) skl[gw] = d;
        else { skl[gw] |= d; vout[gw] = e1v; }
      }
    }
    __syncthreads();
  }
}

// ---------------- combined: fskel tile (blocks 0..1023) + one bskel iter (1024..1151) ------
// MODE 0: fskel2 INIT; 1: fskel2; 2: fskel1 (last d-term).
template<int MODE>
__global__ __launch_bounds__(512) void fsk_b(
    const u16* __restrict__ imgin, u16* __restrict__ imgout, u16* __restrict__ skel,
    const u64* __restrict__ bin, u64* __restrict__ bout, u64* __restrict__ bskl)
{
  __shared__ __align__(16) char smem_[33280];
  int bid = blockIdx.x;
  int tid = threadIdx.x;
  if (bid < 1024){
    int xb = bid&3, yb=(bid>>2)&15, zb=(bid>>6)&7, b=bid>>9;
    int X0=xb*32, Y0=yb*8, Z0=zb*8;
    const u32* vin = (const u32*)(imgin + (size_t)b*VOL);
    u32* skl = (u32*)(skel + (size_t)b*VOL);
    if (MODE < 2){
      u32* A_ = (u32*)smem_;        // 3920
      u32* B_ = A_ + 3920;          // 2592
      u32* C_ = B_ + 2592;          // 1800
      u32* vout = (u32*)(imgout + (size_t)b*VOL);
      // P0: load A, OOB -> 1.0
      for (int idx=tid; idx<3920; idx+=512){
        int z = idx/280; int rem = idx - z*280; int y = rem/20; int px = rem - y*20;
        int gz = Z0-3+z, gy = Y0-3+y, gx = X0-4+2*px;
        bool ok = ((unsigned)gz<64u) & ((unsigned)gy<128u) & ((unsigned)gx<128u);
        A_[idx] = ok ? vin[(gz<<13)+(gy<<6)+(gx>>1)] : H_ONE2;
      }
      __syncthreads();
      // P1: B = erode7(A), OOB word -> 1.0
      for (int idx=tid; idx<2592; idx+=512){
        int z = idx/216; int rem = idx - z*216; int y = rem/18; int px = rem - y*18;
        int gz = Z0-2+z, gy = Y0-2+y;
        bool zok = (unsigned)gz<64u, yok = (unsigned)gy<128u;
        bool xout = ((X0==0)&&(px==0)) || ((X0==96)&&(px==17));
        u32 v = H_ONE2;
        if (zok && yok && !xout){
          int c = (z+1)*280 + (y+1)*20 + (px+1);
          u32 C0=A_[c], L=A_[c-1], R=A_[c+1];
          u32 SL=(L>>16)|(C0<<16), SR=(C0>>16)|(R<<16);
          u32 m = pmin(pmin(SL,SR), C0);
          m = pmin(m, pmin(A_[c-20],A_[c+20]));
          v = pmin(m, pmin(A_[c-280],A_[c+280]));
        }
        B_[idx] = v;
      }
      __syncthreads();
      // P2: C = erode7(B), OOB word -> 0; write E_{k+2} center to global
      for (int idx=tid; idx<1800; idx+=512){
        int z = idx/180; int rem = idx - z*180; int y = rem/18; int px = rem - y*18;
        int gz = Z0-1+z, gy = Y0-1+y;
        bool zok=(unsigned)gz<64u, yok=(unsigned)gy<128u;
        bool xout = ((X0==0)&&(px==0)) || ((X0==96)&&(px==17));
        int pxm = (px>0)?px-1:0, pxp=(px<17)?px+1:17;
        u32 v = 0;
        if (zok && yok && !xout){
          int c = (z+1)*216 + (y+1)*18;
          u32 C0=B_[c+px], L=B_[c+pxm], R=B_[c+pxp];
          u32 SL=(L>>16)|(C0<<16), SR=(C0>>16)|(R<<16);
          u32 m = pmin(pmin(SL,SR), C0);
          m = pmin(m, pmin(B_[c+px-18],B_[c+px+18]));
          v = pmin(m, pmin(B_[c-216+px],B_[c+216+px]));
        }
        C_[idx] = v;
        if (px>=1 && px<=16 && y>=1 && y<=8 && z>=1 && z<=8)
          vout[(gz<<13)+(gy<<6)+((X0-2+2*px)>>1)] = v;
      }
      int zq = tid>>7, cc = tid&127;
      int oy = cc>>4, opx = cc&15;
      u32 ek0[2], ek1[2];
      #pragma unroll
      for(int j=0;j<2;j++){
        int z = zq*2+j;
        ek0[j] = A_[(z+3)*280 + (oy+3)*20 + (opx+2)];
        ek1[j] = B_[(z+2)*216 + (oy+2)*18 + (opx+1)];
      }
      __syncthreads();
      // P3: X1 = xmax(B) (masked), X2 = xmax(C) -> A space
      u32* X1 = A_; u32* X2 = A_ + 1600;
      for (int idx=tid; idx<3200; idx+=512){
        int arr = (idx>=1600);
        int r2 = arr ? idx-1600 : idx;
        int z = r2/160; int rem = r2 - z*160; int y = rem>>4; int px = rem&15;
        u32 v;
        if (!arr){
          int gz = Z0-1+z, gy = Y0-1+y;
          bool ok = ((unsigned)gz<64u) && ((unsigned)gy<128u);
          int c = (z+1)*216 + (y+1)*18 + (px+1);
          u32 C0=B_[c], L=B_[c-1], R=B_[c+1];
          if ((X0==0)&&(px==0)) L=0;
          if ((X0==96)&&(px==15)) R=0;
          u32 SL=(L>>16)|(C0<<16), SR=(C0>>16)|(R<<16);
          v = pmax(pmax(SL,SR), C0);
          if (!ok) v = 0;
        } else {
          int c = z*180 + y*18 + (px+1);
          u32 C0=C_[c], L=C_[c-1], R=C_[c+1];
          u32 SL=(L>>16)|(C0<<16), SR=(C0>>16)|(R<<16);
          v = pmax(pmax(SL,SR), C0);
        }
        A_[idx] = v;
      }
      __syncthreads();
      // P4: Y = ymax(X) -> B space
      for (int idx=tid; idx<2560; idx+=512){
        int arr = (idx>=1280);
        int r2 = arr ? idx-1280 : idx;
        int z = r2>>7; int rem = r2&127; int y = rem>>4; int px = rem&15;
        const u32* Xs = arr ? X2 : X1;
        int c = z*160 + y*16 + px;
        B_[idx] = pmax(pmax(Xs[c], Xs[c+16]), Xs[c+32]);
      }
      __syncthreads();
      // P5: zmax + two skel updates
      u32* Y1 = B_; u32* Y2 = B_ + 1280;
      {
        int gx = X0 + 2*opx;
        #pragma unroll
        for(int j=0;j<2;j++){
          int z = zq*2+j;
          int gz = Z0+z;
          int c = z*128 + oy*16 + opx;
          u32 o1 = pmax(pmax(Y1[c], Y1[c+128]), Y1[c+256]);
          u32 o2 = pmax(pmax(Y2[c], Y2[c+128]), Y2[c+256]);
          u32 idx = (u32)((gz<<13) + ((Y0+oy)<<6) + (gx>>1));
          float d0l = fmaxf(h2f((u16)ek0[j]) - h2f((u16)o1), 0.f);
          float d0h = fmaxf(h2f((u16)(ek0[j]>>16)) - h2f((u16)(o1>>16)), 0.f);
          float d1l = fmaxf(h2f((u16)ek1[j]) - h2f((u16)o2), 0.f);
          float d1h = fmaxf(h2f((u16)(ek1[j]>>16)) - h2f((u16)(o2>>16)), 0.f);
          float sl_, sh_;
          if (MODE==0){ sl_ = d0l; sh_ = d0h; }
          else {
            u32 swv = skl[idx];
            sl_ = h2f((u16)swv); sh_ = h2f((u16)(swv>>16));
            sl_ += fmaxf(d0l - sl_*d0l, 0.f); sh_ += fmaxf(d0h - sh_*d0h, 0.f);
          }
          sl_ += fmaxf(d1l - sl_*d1l, 0.f); sh_ += fmaxf(d1h - sh_*d1h, 0.f);
          skl[idx] = (u32)f2h(sl_) | ((u32)f2h(sh_)<<16);
        }
      }
    } else {
      // fskel1 body
      u32* A2 = (u32*)smem_;        // 2880
      u32* B2 = A2 + 2880;          // 1800
      for (int idx=tid; idx<2880; idx+=512){
        int z = idx/240; int rem = idx - z*240; int y = rem/20; int px = rem - y*20;
        int gz = Z0-2+z, gy = Y0-2+y, gx = X0-4+2*px;
        bool ok = ((unsigned)gz<64u) & ((unsigned)gy<128u) & ((unsigned)gx<128u);
        A2[idx] = ok ? vin[(gz<<13)+(gy<<6)+(gx>>1)] : H_ONE2;
      }
      __syncthreads();
      for (int idx=tid; idx<1800; idx+=512){
        int z = idx/180; int rem = idx - z*180; int y = rem/18; int px = rem - y*18;
        int gz = Z0-1+z, gy = Y0-1+y;
        bool zok=(unsigned)gz<64u, yok=(unsigned)gy<128u;
        bool xout = ((X0==0)&&(px==0)) || ((X0==96)&&(px==17));
        int pxm = (px>0)?px-1:0, pxp=(px<17)?px+1:17;
        u32 v = 0;
        if (zok && yok && !xout){
          int c = (z+1)*240 + (y+1)*20;
          u32 C0=A2[c+px+1], L=A2[c+pxm+1], R=A2[c+pxp+1];
          u32 SL=(L>>16)|(C0<<16), SR=(C0>>16)|(R<<16);
          u32 m = pmin(pmin(SL,SR), C0);
          m = pmin(m, pmin(A2[c+px+1-20],A2[c+px+1+20]));
          v = pmin(m, pmin(A2[c-240+px+1],A2[c+240+px+1]));
        }
        B2[idx] = v;
      }
      int zq = tid>>7, cc = tid&127;
      int oy = cc>>4, opx = cc&15;
      u32 ek[2];
      #pragma unroll
      for(int j=0;j<2;j++){
        int z = zq*2+j;
        ek[j] = A2[(z+2)*240 + (oy+2)*20 + (opx+2)];
      }
      __syncthreads();
      u32* X = A2;
      for (int idx=tid; idx<1600; idx+=512){
        int z = idx/160; int rem = idx - z*160; int y = rem>>4; int px = rem&15;
        int c = z*180 + y*18 + (px+1);
        u32 C0=B2[c], L=B2[c-1], R=B2[c+1];
        u32 SL=(L>>16)|(C0<<16), SR=(C0>>16)|(R<<16);
        A2[idx] = pmax(pmax(SL,SR), C0);
      }
      __syncthreads();
      u32* Y = B2;
      for (int idx=tid; idx<1280; idx+=512){
        int z = idx>>7; int rem = idx&127; int y = rem>>4; int px = rem&15;
        int c = z*160 + y*16 + px;
        B2[idx] = pmax(pmax(X[c], X[c+16]), X[c+32]);
      }
      __syncthreads();
      {
        int gx = X0 + 2*opx;
        #pragma unroll
        for(int j=0;j<2;j++){
          int z = zq*2+j;
          int gz = Z0+z;
          int c = z*128 + oy*16 + opx;
          u32 o = pmax(pmax(Y[c], Y[c+128]), Y[c+256]);
          u32 idx = (u32)((gz<<13) + ((Y0+oy)<<6) + (gx>>1));
          float dl = fmaxf(h2f((u16)ek[j]) - h2f((u16)o), 0.f);
          float dh = fmaxf(h2f((u16)(ek[j]>>16)) - h2f((u16)(o>>16)), 0.f);
          u32 swv = skl[idx];
          float sl_ = h2f((u16)swv), sh_ = h2f((u16)(swv>>16));
          sl_ += fmaxf(dl - sl_*dl, 0.f); sh_ += fmaxf(dh - sh_*dh, 0.f);
          skl[idx] = (u32)f2h(sl_) | ((u32)f2h(sh_)<<16);
        }
      }
    }
  } else {
    // -------- one bskel<false> iteration, blocks 1024..1151 --------
    u64* sim = (u64*)smem_;        // 4*256
    u64* se1 = sim + 1024;         // 6*256
    u64* se2 = se1 + 1536;         // 2*256
    u64* sM  = se2 + 512;          // 4*256
    int bid2 = bid - 1024;
    int tzb = bid2 & 31, b = (bid2>>5)&1, m = bid2>>6;
    int z0 = tzb*2, z1 = z0+2;
    size_t base = (size_t)m*NWORDS + (size_t)b*16384;
    const u64* vin = bin + base;
    u64* vout = bout + base;
    u64* skl = bskl + base;
    int y = tid>>1;
    for (int s = z0-3; s <= z1+6; ++s){
      if (tid < 256){
        if (s <= z1+2)
          sim[((s+96)&3)*256+tid] = ((unsigned)s<64u) ? vin[(s<<8)+tid] : ~0ull;
        { int t = s-2;
          if (t >= z0-2 && t <= z1+1){
            u64 r = ~0ull;
            if ((unsigned)t<64u){
              const u64* P = sim + ((t+96)&3)*256;
              r = berode_x(P, tid);
              if(y>0)   r &= P[tid-2];
              if(y<127) r &= P[tid+2];
              r &= sim[((t-1+96)&3)*256+tid] & sim[((t+1+96)&3)*256+tid];
            }
            se1[((t+96)%6)*256+tid] = r;
          }
        }
        { int t = s-4;
          if (t >= z0-1 && t <= z1){
            u64 r = 0;
            if ((unsigned)t<64u){
              const u64* P = se1 + ((t+96)%6)*256;
              r = berode_x(P, tid);
              if(y>0)   r &= P[tid-2];
              if(y<127) r &= P[tid+2];
              r &= se1[((t-1+96)%6)*256+tid] & se1[((t+1+96)%6)*256+tid];
            }
            se2[((t+96)&1)*256+tid] = r;
          }
        }
        { int t = s-5;
          if (t >= z0-1 && t <= z1){
            const u64* P = se2 + ((t+96)&1)*256;
            u64 dm = bdilate_x(P, tid);
            if(y>0)   dm |= bdilate_x(P, tid-2);
            if(y<127) dm |= bdilate_x(P, tid+2);
            sM[((t+96)&3)*256+tid] = dm;
          }
        }
        { int z = s-7;
          if (z >= z0 && z < z1){
            u64 open_ = sM[((z-1+96)&3)*256+tid] | sM[((z+96)&3)*256+tid] | sM[((z+1+96)&3)*256+tid];
            u64 e1v = se1[((z+96)%6)*256+tid];
            u64 d = e1v & ~open_;
            int gw = (z<<8)+tid;
            skl[gw] |= d;
            vout[gw] = e1v;
          }
        }
      }
      __syncthreads();
    }
  }
}

// ---------------- EDT y-pass (x-pass fused into k_init) ----------------
__global__ __launch_bounds__(256) void edt_py(const u8* __restrict__ din, u8* __restrict__ dout){
  int g = blockIdx.x*256 + threadIdx.x;
  int n = g & (NTOT-1);
  int c = (n >> 7) & 127;
  size_t idx = (size_t)g;
  int best = din[idx];
  #pragma unroll 4
  for (int k=1; k<=16; ++k){
    if (best <= k) break;
    int v = 255;
    if (c-k >= 0)   v = din[idx - (size_t)k*128];
    if (c+k < 128)  v = min(v, (int)din[idx + (size_t)k*128]);
    best = min(best, max(k, v));
  }
  dout[idx] = (u8)best;
}

// z-pass + per-block skeleton-radius max/min partials
__global__ __launch_bounds__(256) void edt_pz_part(const u8* __restrict__ din, u8* __restrict__ dout,
    const u64* __restrict__ skel2, const u64* __restrict__ hbits,
    u8* __restrict__ pmaxv, u8* __restrict__ pminv)
{
  int tid = threadIdx.x;
  int g = blockIdx.x*256 + tid;
  int m = g >> 21;
  int n = g & (NTOT-1);
  int c = (n >> 14) & 63;
  size_t idx = (size_t)g;
  int best = din[idx];
  #pragma unroll 4
  for (int k=1; k<=16; ++k){
    if (best <= k) break;
    int v = 255;
    if (c-k >= 0)  v = din[idx - (size_t)k*16384];
    if (c+k < 64)  v = min(v, (int)din[idx + (size_t)k*16384]);
    best = min(best, max(k, v));
  }
  dout[idx] = (u8)best;
  int wi = n>>6, bit = n&63;
  u64 sbit = m ? (skel2[NWORDS+wi] & hbits[wi]) : skel2[wi];
  u32 r = (u32)((sbit>>bit)&1ull) ? (u32)best : 0u;
  __shared__ u32 sx[256], sn_[256];
  sx[tid]=r; sn_[tid]=r;
  __syncthreads();
  for(int s=128;s>0;s>>=1){
    if(tid<s){
      if(sx[tid+s]>sx[tid]) sx[tid]=sx[tid+s];
      if(sn_[tid+s]<sn_[tid]) sn_[tid]=sn_[tid+s];
    }
    __syncthreads();
  }
  if(tid==0){ pmaxv[blockIdx.x]=(u8)sx[0]; pminv[blockIdx.x]=(u8)sn_[0]; }
}

// reduce 16384 block partials -> mm[8]
__global__ __launch_bounds__(256) void rmm2(const u8* __restrict__ pmaxv, const u8* __restrict__ pminv,
                                            u32* __restrict__ mm){
  __shared__ u8 smx[4][256], smn[4][256];
  int tid = threadIdx.x;
  u8 mx[4]={0,0,0,0}, mn[4]={255,255,255,255};
  for(int i=tid;i<16384;i+=256){
    int sel=i>>13, b=(i>>12)&1, cc=sel*2+b;
    u8 a=pmaxv[i], d=pminv[i];
    if(a>mx[cc]) mx[cc]=a;
    if(d<mn[cc]) mn[cc]=d;
  }
  #pragma unroll
  for(int cc=0;cc<4;cc++){ smx[cc][tid]=mx[cc]; smn[cc][tid]=mn[cc]; }
  __syncthreads();
  for(int s=128;s>0;s>>=1){
    if(tid<s){
      #pragma unroll
      for(int cc=0;cc<4;cc++){
        if(smx[cc][tid+s]>smx[cc][tid]) smx[cc][tid]=smx[cc][tid+s];
        if(smn[cc][tid+s]<smn[cc][tid]) smn[cc][tid]=smn[cc][tid+s];
      }
    }
    __syncthreads();
  }
  if(tid==0){
    #pragma unroll
    for(int cc=0;cc<4;cc++){
      int sel=cc>>1, b=cc&1;
      mm[sel*4+b]   = (u32)smx[cc][0];
      mm[sel*4+2+b] = (u32)smn[cc][0];
    }
  }
}

// ---------------- k_tail: LDS-tiled separable sobel + final reduce (float partials) --------
__global__ __launch_bounds__(256) void k_tail(const float* __restrict__ net, const u16* __restrict__ prob,
    const u16* __restrict__ skelp, const u64* __restrict__ ybits, const u64* __restrict__ hbits,
    const u64* __restrict__ skel2, const u8* __restrict__ acc, const u32* __restrict__ mm,
    double* __restrict__ part1)
{
  __shared__ float lp[2040];
  __shared__ float dxp[1920];
  __shared__ float sxp[1920];
  __shared__ char  dxt8[1920];
  __shared__ u8    sxt8[1920];
  __shared__ u64   wrow[60];
  __shared__ double sw[9][4];
  int tid = threadIdx.x;
  int bid = blockIdx.x;
  int xb = bid&3, ybk=(bid>>2)&15, zbk=(bid>>6)&15, b=bid>>10;
  int X0=xb*32, Y0=ybk*8, Z0=zbk*4;
  const float* P = net + (size_t)b*(2*VOL);
  float rmaxT = fmaxf((float)mm[b],1.f),   rminT = fmaxf((float)mm[2+b],1.f);
  float rmaxH = fmaxf((float)mm[4+b],1.f), rminH = fmaxf((float)mm[6+b],1.f);
  for (int idx=tid; idx<2040; idx+=256){
    int zr = idx/340; int rem = idx-zr*340; int yr = rem/34; int xi = rem-yr*34;
    int gz=Z0-1+zr, gy=Y0-1+yr, gx=X0-1+xi;
    float v = 0.f;
    if((unsigned)gz<64u && (unsigned)gy<128u && (unsigned)gx<128u)
      v = P[(gz<<14)+(gy<<7)+gx];
    lp[idx] = v;
  }
  if (tid < 60){
    int zr = tid/10, yr = tid-zr*10;
    int gz=Z0-1+zr, gy=Y0-1+yr;
    u64 wn = 0;
    if((unsigned)gz<64u && (unsigned)gy<128u){
      const u64* yw = ybits + ((size_t)b<<14) + (gz<<8) + (gy<<1);
      u64 w0 = yw[0], w1 = yw[1];
      if (X0==0) wn = w0<<1;
      else { int s = X0-1; wn = (s<64) ? ((w0>>s)|(w1<<(64-s))) : (w1>>(s-64)); }
    }
    wrow[tid] = wn;
  }
  __syncthreads();
  for (int idx=tid; idx<1920; idx+=256){
    int zr = idx/320; int rem = idx-zr*320; int yr = rem>>5; int x = rem&31;
    int c = zr*340 + yr*34 + x;
    float l0=lp[c], l1=lp[c+1], l2=lp[c+2];
    dxp[idx] = l2-l0;
    sxp[idx] = l0+2.f*l1+l2;
    u64 wn = wrow[zr*10+yr];
    int bm=(int)((wn>>x)&1ull), b1=(int)((wn>>(x+1))&1ull), bp=(int)((wn>>(x+2))&1ull);
    dxt8[idx] = (char)(bp-bm);
    sxt8[idx] = (u8)(bm+2*b1+bp);
  }
  __syncthreads();
  int oy = tid>>5, ox = tid&31;
  float A1[6],A2[6],A3[6];
  int   B1v[6],B2v[6],B3v[6];
  #pragma unroll
  for(int zr=0; zr<6; ++zr){
    int base = zr*320 + oy*32 + ox;
    float d0=dxp[base], d1=dxp[base+32], d2=dxp[base+64];
    A1[zr] = d0+2.f*d1+d2;
    A2[zr] = d0+d1+d2;
    float s0=sxp[base], s1=sxp[base+32], s2=sxp[base+64];
    A3[zr] = s0+s1+s2;
    int t0=dxt8[base], t1=dxt8[base+32], t2=dxt8[base+64];
    B1v[zr] = t0+2*t1+t2;
    B2v[zr] = t0+t1+t2;
    int u0=sxt8[base], u1=sxt8[base+32], u2=sxt8[base+64];
    B3v[zr] = u0+u1+u2;
  }
  float fsob=0,cl1=0,cl2=0,cl3=0,cl4=0,i1=0,un1=0,i2=0,un2=0;
  #pragma unroll
  for(int zc=0; zc<4; ++zc){
    float gpx = A1[zc]+A1[zc+1]+A1[zc+2];
    float gpy = A2[zc]+2.f*A2[zc+1]+A2[zc+2];
    float gpz = A3[zc+2]-A3[zc];
    float ftx = (float)(B1v[zc]+B1v[zc+1]+B1v[zc+2]);
    float fty = (float)(B2v[zc]+2*B2v[zc+1]+B2v[zc+2]);
    float ftz = (float)(B3v[zc+2]-B3v[zc]);
    float s1 = gpx*gpx+gpy*gpy+gpz*gpz;
    float s2 = ftx*ftx+fty*fty+ftz*ftz;
    if (s1>0.f && s2>0.f){
      float ip = rsqrtf(s1), it = rsqrtf(s2);
      fsob += (gpx*ftx+gpy*fty+gpz*ftz)*ip*it;
    }
    int gz=Z0+zc, gy=Y0+oy, gx=X0+ox;
    int n = (b<<20)+(gz<<14)+(gy<<7)+gx;
    int yb = (int)((wrow[(zc+1)*10+(oy+1)] >> (ox+1)) & 1ull);
    int wi = n>>6, bit = n&63;
    int hd = (int)((hbits[wi]>>bit)&1ull);
    int sT = (int)((skel2[wi]>>bit)&1ull);
    int sH = (int)((skel2[NWORDS+wi]>>bit)&1ull);
    float dT = (float)acc[n];
    float dH = (float)acc[(size_t)NTOT+n];
    float p  = h2f(prob[n]);
    float sk = h2f(skelp[n]);
    cl1 += sk*(float)yb;
    cl2 += sk;
    float q_vl = yb ? fminf(dT,rmaxT)/rmaxT : 0.f;
    if (sT){
      cl3 += p; cl4 += 1.f;
      float t=(rmaxT-dT+rminT)/rmaxT; float q_sl=t*t;
      float q_vp = fminf(dH,rmaxH)/rmaxH*p;
      i2  += q_sl*__powf(q_vp+1e-4f,0.7f)*q_sl;
      un2 += q_sl*(0.1f*q_vp+0.9f*q_sl);
    }
    if (sH & hd){
      float t=(rmaxH-dH+rminH)/rmaxH; float q_sp=t*t*p;
      i1  += q_sp*__powf(q_sp+1e-4f,0.7f)*q_vl;
      un1 += q_sp*(0.1f*q_sp+0.9f*q_vl);
    }
  }
  int wid = tid>>6, lane = tid&63;
  double vals[9] = {(double)fsob,(double)cl1,(double)cl2,(double)cl3,(double)cl4,
                    (double)i1,(double)un1,(double)i2,(double)un2};
  #pragma unroll
  for(int s=0;s<9;s++){ double rr = wred(vals[s]); if(lane==0) sw[s][wid]=rr; }
  __syncthreads();
  if(tid==0){
    #pragma unroll
    for(int s=0;s<9;s++) part1[(size_t)s*PC1 + bid] = sw[s][0]+sw[s][1]+sw[s][2]+sw[s][3];
  }
}

// ---------------- two-stage finalize ----------------
__global__ __launch_bounds__(256) void k_reduce_mid(const double* __restrict__ part0,
                                                    const double* __restrict__ part1,
                                                    double* __restrict__ tot){
  int s = blockIdx.x;
  const double* src; int n;
  if (s < 5){ src = part0 + (size_t)s*PC0; n = PC0; }
  else      { src = part1 + (size_t)(s-5)*PC1; n = PC1; }
  double v=0;
  for(int i=threadIdx.x;i<n;i+=256) v += src[i];
  __shared__ double sd[256];
  sd[threadIdx.x]=v; __syncthreads();
  for(int k=128;k>0;k>>=1){ if((int)threadIdx.x<k) sd[threadIdx.x]+=sd[threadIdx.x+k]; __syncthreads(); }
  if(threadIdx.x==0) tot[s]=sd[0];
}

__global__ void k_fin(const double* __restrict__ tot, float* __restrict__ out){
  if(threadIdx.x==0 && blockIdx.x==0){
    const double N = (double)NTOT;
    double ce = tot[0]/N;
    double tp=tot[1], fp=tot[2]-tot[1], fn=tot[3]-tot[1];
    double dice = -((2.0*tp+1e-5)/(2.0*tp+fp+fn+1e-5));
    double conn = tot[4]/(2.0*N);
    double dir  = 1.0 - tot[5]/N;
    double tprec = (tot[6]+1.0)/(tot[7]+1.0);
    double tsens = (tot[8]+1.0)/(tot[9]+1.0);
    double cld = 1.0 - 2.0*tprec*tsens/(tprec+tsens);
    double u1 = 1.0 - (tot[10]+1.0)/(tot[11]+1.0);
    double u2 = 1.0 - (tot[12]+1.0)/(tot[13]+1.0);
    out[0] = (float)(dice+ce+cld+dir+conn+u1+u2);
  }
}

extern "C" void kernel_launch(void* const* d_in, const int* in_sizes, int n_in,
                              void* d_out, int out_size, void* d_ws, size_t ws_size,
                              hipStream_t stream)
{
  (void)in_sizes; (void)n_in; (void)out_size; (void)ws_size;
  const float* net = (const float*)d_in[0];
  const int*   tgt = (const int*)d_in[1];
  float* out = (float*)d_out;
  char* w = (char*)d_ws;
  const size_t MB = 1024*1024;
  u16* F1 = (u16*)(w + 0*MB);              // prob img ping (fp16)
  u16* F2 = (u16*)(w + 4*MB);              // skel_pred
  u16* F3 = (u16*)(w + 8*MB);              // img pong
  u16* F4 = (u16*)(w + 12*MB);             // pristine prob copy
  u64* ybits = (u64*)(w + 16*MB);
  u64* hbits = ybits + NWORDS;
  u64* skel2 = hbits + NWORDS;
  u64* bping = skel2 + 2*NWORDS;
  u64* bpong = bping + 2*NWORDS;
  u8*  dA    = (u8*)(bpong + 2*NWORDS);
  u8*  dB    = dA + (size_t)2*NTOT;
  double* part0 = (double*)(dB + (size_t)2*NTOT);
  double* part1 = part0 + (size_t)5*PC0;
  double* tot   = part1 + (size_t)9*PC1;
  u8* pmaxv = (u8*)(tot + 16);
  u8* pminv = pmaxv + 16384;
  u32* mm  = (u32*)(pminv + 16384);

  k_init<<<PC0, 256, 0, stream>>>(net, tgt, F1, F4, ybits, hbits, bping, dA, part0);

  // binary skeleton: INIT + 4 false iterations standalone
  bskel<true><<<128,256,0,stream>>>(bping, bpong, skel2);
  bskel<false><<<128,256,0,stream>>>(bping, bpong, skel2);
  bskel<false><<<128,256,0,stream>>>(bpong, bping, skel2);
  bskel<false><<<128,256,0,stream>>>(bping, bpong, skel2);
  bskel<false><<<128,256,0,stream>>>(bpong, bping, skel2);

  // fskel chain (6 dispatches) with bskel false #5..#10 piggybacked (blocks 1024..1151)
  fsk_b<0><<<1152,512,0,stream>>>(F1, F3, F2, bping, bpong, skel2);
  fsk_b<1><<<1152,512,0,stream>>>(F3, F1, F2, bpong, bping, skel2);
  fsk_b<1><<<1152,512,0,stream>>>(F1, F3, F2, bping, bpong, skel2);
  fsk_b<1><<<1152,512,0,stream>>>(F3, F1, F2, bpong, bping, skel2);
  fsk_b<1><<<1152,512,0,stream>>>(F1, F3, F2, bping, bpong, skel2);
  fsk_b<2><<<1152,512,0,stream>>>(F3, F1, F2, bpong, bping, skel2);

  const int GE = (2*NTOT)/256;
  edt_py<<<GE,256,0,stream>>>(dA, dB);
  edt_pz_part<<<GE,256,0,stream>>>(dB, dA, skel2, hbits, pmaxv, pminv);
  rmm2<<<1,256,0,stream>>>(pmaxv, pminv, mm);

  k_tail<<<PC1,256,0,stream>>>(net, F4, F2, ybits, hbits, skel2, dA, mm, part1);
  k_reduce_mid<<<14,256,0,stream>>>(part0, part1, tot);
  k_fin<<<1,64,0,stream>>>(tot, out);
}

// Round 17
// 259.849 us; speedup vs baseline: 1.0569x; 1.0457x over previous
//
#include <hip/hip_runtime.h>
#include <math.h>

typedef unsigned long long u64;
typedef unsigned int u32;
typedef unsigned short u16;
typedef unsigned char u8;

#define VOL 1048576              // 64*128*128
#define NTOT 2097152             // 2 batches
#define NWORDS 32768             // NTOT/64
#define PC0 2048
#define PC1 2048

union HU { u16 u; _Float16 h; };
__device__ __forceinline__ float h2f(u16 u){ HU x; x.u=u; return (float)x.h; }
__device__ __forceinline__ u16 f2h(float f){ HU x; x.h=(_Float16)f; return x.u; }
#define H_ONE2 0x3C003C00u   // pair of 1.0 (erode-neutral)

__device__ __forceinline__ u32 pmin(u32 a, u32 b){ u32 r; asm("v_pk_min_f16 %0, %1, %2" : "=v"(r) : "v"(a), "v"(b)); return r; }
__device__ __forceinline__ u32 pmax(u32 a, u32 b){ u32 r; asm("v_pk_max_f16 %0, %1, %2" : "=v"(r) : "v"(a), "v"(b)); return r; }

__device__ __forceinline__ double wred(double v){
  #pragma unroll
  for(int o=32;o;o>>=1) v += __shfl_down(v, o);
  return v;
}

__device__ __forceinline__ u32 nib_compact(u64 v){
  v &= 0x0F0F0F0F0F0F0F0Full;
  v |= v>>4;  v &= 0x00FF00FF00FF00FFull;
  v |= v>>8;  v &= 0x0000FFFF0000FFFFull;
  v |= v>>16;
  return (u32)v;
}

// x-EDT for one voxel from its row's two bitwords
__device__ __forceinline__ int edt_x1(u64 w0, u64 w1, int x){
  int a = x-31;
  u64 win;
  if (a<0)        win = w0 << (-a);
  else if (a==0)  win = w0;
  else if (a<64)  win = (w0>>a)|(w1<<(64-a));
  else            win = w1>>(a-64);
  if (x<31) win |= (1ull<<(31-x))-1;
  if (x>95) win |= (~0ull)<<(159-x);
  u64 inv = ~win;
  u64 tl = inv & 0xFFFFFFFFull;
  u64 tr = inv>>31;
  int dl = tl ? (31-(63-__clzll(tl))) : 99;
  int dr = tr ? (__ffsll((unsigned long long)tr)-1) : 99;
  return min(min(dl,dr),16);
}

// EDT y-pass body for one element
__device__ __forceinline__ void edt_py_one(const u8* __restrict__ din, u8* __restrict__ dout, int g){
  int n = g & (NTOT-1);
  int c = (n >> 7) & 127;
  size_t idx = (size_t)g;
  int best = din[idx];
  #pragma unroll 4
  for (int k=1; k<=16; ++k){
    if (best <= k) break;
    int v = 255;
    if (c-k >= 0)   v = din[idx - (size_t)k*128];
    if (c+k < 128)  v = min(v, (int)din[idx + (size_t)k*128]);
    best = min(best, max(k, v));
  }
  dout[idx] = (u8)best;
}

// ---------------- init: prob(fp16 x2), bitmasks, fused x-EDT, sums (float partials) --------
__global__ __launch_bounds__(256) void k_init(const float* __restrict__ net, const int* __restrict__ tgt,
    u16* __restrict__ img, u16* __restrict__ prob, u64* __restrict__ ybits, u64* __restrict__ hbits,
    u64* __restrict__ bimg2, u8* __restrict__ dA, double* __restrict__ part)
{
  __shared__ u64 nyb[32], nhb[32];
  __shared__ u64 swy[16], swh[16];
  __shared__ double sw[5][4];
  int tid = threadIdx.x;
  int r = blockIdx.x*256 + tid;
  int n0 = r<<2;
  int b = n0>>20, v0 = n0&(VOL-1);
  const float* nb = net + (size_t)b*(2*VOL);
  float4 a0 = *(const float4*)&nb[v0];
  float4 a1 = *(const float4*)&nb[VOL+v0];
  int4  tv = *(const int4*)&tgt[n0];
  float x0a[4] = {a0.x,a0.y,a0.z,a0.w};
  float x1a[4] = {a1.x,a1.y,a1.z,a1.w};
  int   ta[4]  = {tv.x,tv.y,tv.z,tv.w};
  float ce=0,tp=0,spr=0,sy=0,conn=0;
  u32 pk[2] = {0,0};
  u32 y4=0, h4=0;
  #pragma unroll
  for(int e=0;e<4;e++){
    float d = x1a[e]-x0a[e];
    int yb = (ta[e]>0) ? 1 : 0;
    float p = 1.f/(1.f+__expf(-d));
    y4 |= (u32)yb<<e;
    h4 |= (u32)(d>0.f)<<e;
    pk[e>>1] |= (u32)f2h(p) << ((e&1)*16);
    ce += __logf(1.f+__expf(-fabsf(d))) + fmaxf(yb? -d : d, 0.f);
    tp += p*(float)yb;
    spr += p;
    sy += (float)yb;
    conn += (float)((int)((x0a[e]>0.5f)!=(yb!=0)) + (int)((x1a[e]>0.5f)!=(yb!=0)));
  }
  u32* f1 = (u32*)img;
  u32* f4 = (u32*)prob;
  int pi = r<<1;
  f1[pi] = pk[0]; f1[pi+1] = pk[1];
  f4[pi] = pk[0]; f4[pi+1] = pk[1];
  ((u8*)nyb)[tid] = (u8)y4;
  ((u8*)nhb)[tid] = (u8)h4;
  __syncthreads();
  if (tid < 16){
    u64 wy = (u64)nib_compact(nyb[tid*2]) | ((u64)nib_compact(nyb[tid*2+1])<<32);
    u64 wh = (u64)nib_compact(nhb[tid*2]) | ((u64)nib_compact(nhb[tid*2+1])<<32);
    int wi = blockIdx.x*16 + tid;
    ybits[wi]=wy; bimg2[wi]=wy;
    hbits[wi]=wh; bimg2[NWORDS+wi]=wh;
    swy[tid]=wy; swh[tid]=wh;
  }
  __syncthreads();
  {
    int ln = tid<<2;
    int row = ln>>7;
    int xq = ln&127;
    int gn0 = blockIdx.x*1024 + ln;
    u64 wy0 = swy[row*2], wy1 = swy[row*2+1];
    u64 wh0 = swh[row*2], wh1 = swh[row*2+1];
    u32 oy4=0, oh4=0;
    #pragma unroll
    for(int e=0;e<4;e++){
      oy4 |= (u32)edt_x1(wy0,wy1,xq+e) << (8*e);
      oh4 |= (u32)edt_x1(wh0,wh1,xq+e) << (8*e);
    }
    *(u32*)&dA[gn0] = oy4;
    *(u32*)&dA[(size_t)NTOT+gn0] = oh4;
  }
  int wid = tid>>6, lane = tid&63;
  double vals[5] = {(double)ce,(double)tp,(double)spr,(double)sy,(double)conn};
  #pragma unroll
  for(int s=0;s<5;s++){ double rr = wred(vals[s]); if(lane==0) sw[s][wid]=rr; }
  __syncthreads();
  if(tid==0){
    #pragma unroll
    for(int s=0;s<5;s++) part[(size_t)s*PC0 + blockIdx.x] = sw[s][0]+sw[s][1]+sw[s][2]+sw[s][3];
  }
}

// ---------------- binary morphology helpers ----------------
__device__ __forceinline__ u64 berode_x(const u64* P, int t){
  u64 c = P[t];
  if (t & 1) return c & ((c<<1)|(P[t-1]>>63)) & ((c>>1)|(1ull<<63));
  else       return c & ((c<<1)|1ull) & ((c>>1)|(P[t+1]<<63));
}
__device__ __forceinline__ u64 bdilate_x(const u64* P, int t){
  u64 c = P[t];
  if (t & 1) return c | (c<<1) | (P[t-1]>>63) | (c>>1);
  else       return c | (c<<1) | (c>>1) | (P[t+1]<<63);
}

// standalone bskel (256 threads) — first 5 iterations
template<bool INIT>
__global__ __launch_bounds__(256) void bskel(const u64* __restrict__ imgin, u64* __restrict__ imgout,
                                             u64* __restrict__ skel)
{
  __shared__ u64 simg[4][256];
  __shared__ u64 se1[6][256];
  __shared__ u64 se2[2][256];
  __shared__ u64 sM[4][256];
  int bid = blockIdx.x;
  int tzb = bid & 31, b = (bid>>5)&1, m = bid>>6;
  int z0 = tzb*2, z1 = z0+2;
  size_t base = (size_t)m*NWORDS + (size_t)b*16384;
  const u64* vin = imgin + base;
  u64* vout = imgout + base;
  u64* skl = skel + base;
  int tid = threadIdx.x;
  int y = tid>>1;

  for (int s = z0-3; s <= z1+6; ++s){
    if (s <= z1+2)
      simg[(s+96)&3][tid] = ((unsigned)s<64u) ? vin[(s<<8)+tid] : ~0ull;
    { int t = s-2;
      if (t >= z0-2 && t <= z1+1){
        u64 r = ~0ull;
        if ((unsigned)t<64u){
          const u64* P = simg[(t+96)&3];
          if (INIT) r = P[tid];
          else {
            r = berode_x(P, tid);
            if(y>0)   r &= P[tid-2];
            if(y<127) r &= P[tid+2];
            r &= simg[(t-1+96)&3][tid] & simg[(t+1+96)&3][tid];
          }
        }
        se1[(t+96)%6][tid] = r;
      }
    }
    { int t = s-4;
      if (t >= z0-1 && t <= z1){
        u64 r = 0;
        if ((unsigned)t<64u){
          const u64* P = se1[(t+96)%6];
          r = berode_x(P, tid);
          if(y>0)   r &= P[tid-2];
          if(y<127) r &= P[tid+2];
          r &= se1[(t-1+96)%6][tid] & se1[(t+1+96)%6][tid];
        }
        se2[(t+96)&1][tid] = r;
      }
    }
    { int t = s-5;
      if (t >= z0-1 && t <= z1){
        const u64* P = se2[(t+96)&1];
        u64 dm = bdilate_x(P, tid);
        if(y>0)   dm |= bdilate_x(P, tid-2);
        if(y<127) dm |= bdilate_x(P, tid+2);
        sM[(t+96)&3][tid] = dm;
      }
    }
    { int z = s-7;
      if (z >= z0 && z < z1){
        u64 open_ = sM[(z-1+96)&3][tid] | sM[(z+96)&3][tid] | sM[(z+1+96)&3][tid];
        u64 e1v = se1[(z+96)%6][tid];
        u64 d = e1v & ~open_;
        int gw = (z<<8)+tid;
        if (INIT) skl[gw] = d;
        else { skl[gw] |= d; vout[gw] = e1v; }
      }
    }
    __syncthreads();
  }
}

// ---------------- combined: fskel tile (0..1023) + bskel iter (1024..1151) + opt edt_py ----
// MODE 0: fskel2 INIT; 1: fskel2; 2: fskel1 (last d-term).
template<int MODE>
__global__ __launch_bounds__(512) void fsk_b(
    const u16* __restrict__ imgin, u16* __restrict__ imgout, u16* __restrict__ skel,
    const u64* __restrict__ bin, u64* __restrict__ bout, u64* __restrict__ bskl,
    const u8* __restrict__ pyin, u8* __restrict__ pyout)
{
  __shared__ __align__(16) char smem_[33280];
  int bid = blockIdx.x;
  int tid = threadIdx.x;
  if (bid < 1024){
    int xb = bid&3, yb=(bid>>2)&15, zb=(bid>>6)&7, b=bid>>9;
    int X0=xb*32, Y0=yb*8, Z0=zb*8;
    const u32* vin = (const u32*)(imgin + (size_t)b*VOL);
    u32* skl = (u32*)(skel + (size_t)b*VOL);
    if (MODE < 2){
      u32* A_ = (u32*)smem_;        // 3920
      u32* B_ = A_ + 3920;          // 2592
      u32* C_ = B_ + 2592;          // 1800
      u32* vout = (u32*)(imgout + (size_t)b*VOL);
      for (int idx=tid; idx<3920; idx+=512){
        int z = idx/280; int rem = idx - z*280; int y = rem/20; int px = rem - y*20;
        int gz = Z0-3+z, gy = Y0-3+y, gx = X0-4+2*px;
        bool ok = ((unsigned)gz<64u) & ((unsigned)gy<128u) & ((unsigned)gx<128u);
        A_[idx] = ok ? vin[(gz<<13)+(gy<<6)+(gx>>1)] : H_ONE2;
      }
      __syncthreads();
      for (int idx=tid; idx<2592; idx+=512){
        int z = idx/216; int rem = idx - z*216; int y = rem/18; int px = rem - y*18;
        int gz = Z0-2+z, gy = Y0-2+y;
        bool zok = (unsigned)gz<64u, yok = (unsigned)gy<128u;
        bool xout = ((X0==0)&&(px==0)) || ((X0==96)&&(px==17));
        u32 v = H_ONE2;
        if (zok && yok && !xout){
          int c = (z+1)*280 + (y+1)*20 + (px+1);
          u32 C0=A_[c], L=A_[c-1], R=A_[c+1];
          u32 SL=(L>>16)|(C0<<16), SR=(C0>>16)|(R<<16);
          u32 m = pmin(pmin(SL,SR), C0);
          m = pmin(m, pmin(A_[c-20],A_[c+20]));
          v = pmin(m, pmin(A_[c-280],A_[c+280]));
        }
        B_[idx] = v;
      }
      __syncthreads();
      for (int idx=tid; idx<1800; idx+=512){
        int z = idx/180; int rem = idx - z*180; int y = rem/18; int px = rem - y*18;
        int gz = Z0-1+z, gy = Y0-1+y;
        bool zok=(unsigned)gz<64u, yok=(unsigned)gy<128u;
        bool xout = ((X0==0)&&(px==0)) || ((X0==96)&&(px==17));
        int pxm = (px>0)?px-1:0, pxp=(px<17)?px+1:17;
        u32 v = 0;
        if (zok && yok && !xout){
          int c = (z+1)*216 + (y+1)*18;
          u32 C0=B_[c+px], L=B_[c+pxm], R=B_[c+pxp];
          u32 SL=(L>>16)|(C0<<16), SR=(C0>>16)|(R<<16);
          u32 m = pmin(pmin(SL,SR), C0);
          m = pmin(m, pmin(B_[c+px-18],B_[c+px+18]));
          v = pmin(m, pmin(B_[c-216+px],B_[c+216+px]));
        }
        C_[idx] = v;
        if (px>=1 && px<=16 && y>=1 && y<=8 && z>=1 && z<=8)
          vout[(gz<<13)+(gy<<6)+((X0-2+2*px)>>1)] = v;
      }
      int zq = tid>>7, cc = tid&127;
      int oy = cc>>4, opx = cc&15;
      u32 ek0[2], ek1[2];
      #pragma unroll
      for(int j=0;j<2;j++){
        int z = zq*2+j;
        ek0[j] = A_[(z+3)*280 + (oy+3)*20 + (opx+2)];
        ek1[j] = B_[(z+2)*216 + (oy+2)*18 + (opx+1)];
      }
      __syncthreads();
      u32* X1 = A_; u32* X2 = A_ + 1600;
      for (int idx=tid; idx<3200; idx+=512){
        int arr = (idx>=1600);
        int r2 = arr ? idx-1600 : idx;
        int z = r2/160; int rem = r2 - z*160; int y = rem>>4; int px = rem&15;
        u32 v;
        if (!arr){
          int gz = Z0-1+z, gy = Y0-1+y;
          bool ok = ((unsigned)gz<64u) && ((unsigned)gy<128u);
          int c = (z+1)*216 + (y+1)*18 + (px+1);
          u32 C0=B_[c], L=B_[c-1], R=B_[c+1];
          if ((X0==0)&&(px==0)) L=0;
          if ((X0==96)&&(px==15)) R=0;
          u32 SL=(L>>16)|(C0<<16), SR=(C0>>16)|(R<<16);
          v = pmax(pmax(SL,SR), C0);
          if (!ok) v = 0;
        } else {
          int c = z*180 + y*18 + (px+1);
          u32 C0=C_[c], L=C_[c-1], R=C_[c+1];
          u32 SL=(L>>16)|(C0<<16), SR=(C0>>16)|(R<<16);
          v = pmax(pmax(SL,SR), C0);
        }
        A_[idx] = v;
      }
      __syncthreads();
      for (int idx=tid; idx<2560; idx+=512){
        int arr = (idx>=1280);
        int r2 = arr ? idx-1280 : idx;
        int z = r2>>7; int rem = r2&127; int y = rem>>4; int px = rem&15;
        const u32* Xs = arr ? X2 : X1;
        int c = z*160 + y*16 + px;
        B_[idx] = pmax(pmax(Xs[c], Xs[c+16]), Xs[c+32]);
      }
      __syncthreads();
      u32* Y1 = B_; u32* Y2 = B_ + 1280;
      {
        int gx = X0 + 2*opx;
        #pragma unroll
        for(int j=0;j<2;j++){
          int z = zq*2+j;
          int gz = Z0+z;
          int c = z*128 + oy*16 + opx;
          u32 o1 = pmax(pmax(Y1[c], Y1[c+128]), Y1[c+256]);
          u32 o2 = pmax(pmax(Y2[c], Y2[c+128]), Y2[c+256]);
          u32 idx = (u32)((gz<<13) + ((Y0+oy)<<6) + (gx>>1));
          float d0l = fmaxf(h2f((u16)ek0[j]) - h2f((u16)o1), 0.f);
          float d0h = fmaxf(h2f((u16)(ek0[j]>>16)) - h2f((u16)(o1>>16)), 0.f);
          float d1l = fmaxf(h2f((u16)ek1[j]) - h2f((u16)o2), 0.f);
          float d1h = fmaxf(h2f((u16)(ek1[j]>>16)) - h2f((u16)(o2>>16)), 0.f);
          float sl_, sh_;
          if (MODE==0){ sl_ = d0l; sh_ = d0h; }
          else {
            u32 swv = skl[idx];
            sl_ = h2f((u16)swv); sh_ = h2f((u16)(swv>>16));
            sl_ += fmaxf(d0l - sl_*d0l, 0.f); sh_ += fmaxf(d0h - sh_*d0h, 0.f);
          }
          sl_ += fmaxf(d1l - sl_*d1l, 0.f); sh_ += fmaxf(d1h - sh_*d1h, 0.f);
          skl[idx] = (u32)f2h(sl_) | ((u32)f2h(sh_)<<16);
        }
      }
    } else {
      // fskel1 body
      u32* A2 = (u32*)smem_;        // 2880
      u32* B2 = A2 + 2880;          // 1800
      for (int idx=tid; idx<2880; idx+=512){
        int z = idx/240; int rem = idx - z*240; int y = rem/20; int px = rem - y*20;
        int gz = Z0-2+z, gy = Y0-2+y, gx = X0-4+2*px;
        bool ok = ((unsigned)gz<64u) & ((unsigned)gy<128u) & ((unsigned)gx<128u);
        A2[idx] = ok ? vin[(gz<<13)+(gy<<6)+(gx>>1)] : H_ONE2;
      }
      __syncthreads();
      for (int idx=tid; idx<1800; idx+=512){
        int z = idx/180; int rem = idx - z*180; int y = rem/18; int px = rem - y*18;
        int gz = Z0-1+z, gy = Y0-1+y;
        bool zok=(unsigned)gz<64u, yok=(unsigned)gy<128u;
        bool xout = ((X0==0)&&(px==0)) || ((X0==96)&&(px==17));
        int pxm = (px>0)?px-1:0, pxp=(px<17)?px+1:17;
        u32 v = 0;
        if (zok && yok && !xout){
          int c = (z+1)*240 + (y+1)*20;
          u32 C0=A2[c+px+1], L=A2[c+pxm+1], R=A2[c+pxp+1];
          u32 SL=(L>>16)|(C0<<16), SR=(C0>>16)|(R<<16);
          u32 m = pmin(pmin(SL,SR), C0);
          m = pmin(m, pmin(A2[c+px+1-20],A2[c+px+1+20]));
          v = pmin(m, pmin(A2[c-240+px+1],A2[c+240+px+1]));
        }
        B2[idx] = v;
      }
      int zq = tid>>7, cc = tid&127;
      int oy = cc>>4, opx = cc&15;
      u32 ek[2];
      #pragma unroll
      for(int j=0;j<2;j++){
        int z = zq*2+j;
        ek[j] = A2[(z+2)*240 + (oy+2)*20 + (opx+2)];
      }
      __syncthreads();
      u32* X = A2;
      for (int idx=tid; idx<1600; idx+=512){
        int z = idx/160; int rem = idx - z*160; int y = rem>>4; int px = rem&15;
        int c = z*180 + y*18 + (px+1);
        u32 C0=B2[c], L=B2[c-1], R=B2[c+1];
        u32 SL=(L>>16)|(C0<<16), SR=(C0>>16)|(R<<16);
        A2[idx] = pmax(pmax(SL,SR), C0);
      }
      __syncthreads();
      u32* Y = B2;
      for (int idx=tid; idx<1280; idx+=512){
        int z = idx>>7; int rem = idx&127; int y = rem>>4; int px = rem&15;
        int c = z*160 + y*16 + px;
        B2[idx] = pmax(pmax(X[c], X[c+16]), X[c+32]);
      }
      __syncthreads();
      {
        int gx = X0 + 2*opx;
        #pragma unroll
        for(int j=0;j<2;j++){
          int z = zq*2+j;
          int gz = Z0+z;
          int c = z*128 + oy*16 + opx;
          u32 o = pmax(pmax(Y[c], Y[c+128]), Y[c+256]);
          u32 idx = (u32)((gz<<13) + ((Y0+oy)<<6) + (gx>>1));
          float dl = fmaxf(h2f((u16)ek[j]) - h2f((u16)o), 0.f);
          float dh = fmaxf(h2f((u16)(ek[j]>>16)) - h2f((u16)(o>>16)), 0.f);
          u32 swv = skl[idx];
          float sl_ = h2f((u16)swv), sh_ = h2f((u16)(swv>>16));
          sl_ += fmaxf(dl - sl_*dl, 0.f); sh_ += fmaxf(dh - sh_*dh, 0.f);
          skl[idx] = (u32)f2h(sl_) | ((u32)f2h(sh_)<<16);
        }
      }
    }
  } else if (bid < 1152){
    // -------- one bskel<false> iteration, blocks 1024..1151 --------
    u64* sim = (u64*)smem_;
    u64* se1 = sim + 1024;
    u64* se2 = se1 + 1536;
    u64* sM  = se2 + 512;
    int bid2 = bid - 1024;
    int tzb = bid2 & 31, b = (bid2>>5)&1, m = bid2>>6;
    int z0 = tzb*2, z1 = z0+2;
    size_t base = (size_t)m*NWORDS + (size_t)b*16384;
    const u64* vin = bin + base;
    u64* vout = bout + base;
    u64* skl = bskl + base;
    int y = tid>>1;
    for (int s = z0-3; s <= z1+6; ++s){
      if (tid < 256){
        if (s <= z1+2)
          sim[((s+96)&3)*256+tid] = ((unsigned)s<64u) ? vin[(s<<8)+tid] : ~0ull;
        { int t = s-2;
          if (t >= z0-2 && t <= z1+1){
            u64 r = ~0ull;
            if ((unsigned)t<64u){
              const u64* P = sim + ((t+96)&3)*256;
              r = berode_x(P, tid);
              if(y>0)   r &= P[tid-2];
              if(y<127) r &= P[tid+2];
              r &= sim[((t-1+96)&3)*256+tid] & sim[((t+1+96)&3)*256+tid];
            }
            se1[((t+96)%6)*256+tid] = r;
          }
        }
        { int t = s-4;
          if (t >= z0-1 && t <= z1){
            u64 r = 0;
            if ((unsigned)t<64u){
              const u64* P = se1 + ((t+96)%6)*256;
              r = berode_x(P, tid);
              if(y>0)   r &= P[tid-2];
              if(y<127) r &= P[tid+2];
              r &= se1[((t-1+96)%6)*256+tid] & se1[((t+1+96)%6)*256+tid];
            }
            se2[((t+96)&1)*256+tid] = r;
          }
        }
        { int t = s-5;
          if (t >= z0-1 && t <= z1){
            const u64* P = se2 + ((t+96)&1)*256;
            u64 dm = bdilate_x(P, tid);
            if(y>0)   dm |= bdilate_x(P, tid-2);
            if(y<127) dm |= bdilate_x(P, tid+2);
            sM[((t+96)&3)*256+tid] = dm;
          }
        }
        { int z = s-7;
          if (z >= z0 && z < z1){
            u64 open_ = sM[((z-1+96)&3)*256+tid] | sM[((z+96)&3)*256+tid] | sM[((z+1+96)&3)*256+tid];
            u64 e1v = se1[((z+96)%6)*256+tid];
            u64 d = e1v & ~open_;
            int gw = (z<<8)+tid;
            skl[gw] |= d;
            vout[gw] = e1v;
          }
        }
      }
      __syncthreads();
    }
  } else {
    // -------- piggybacked EDT y-pass, blocks 1152.. (MODE 0 dispatch only) --------
    int eb = bid - 1152;                 // 0..2047
    int g0 = (eb<<11) + (tid<<2);        // 2048 blocks * 512 thr * 4 = 2*NTOT
    edt_py_one(pyin, pyout, g0);
    edt_py_one(pyin, pyout, g0+1);
    edt_py_one(pyin, pyout, g0+2);
    edt_py_one(pyin, pyout, g0+3);
  }
}

// z-pass + per-block skeleton-radius max/min partials
__global__ __launch_bounds__(256) void edt_pz_part(const u8* __restrict__ din, u8* __restrict__ dout,
    const u64* __restrict__ skel2, const u64* __restrict__ hbits,
    u8* __restrict__ pmaxv, u8* __restrict__ pminv)
{
  int tid = threadIdx.x;
  int g = blockIdx.x*256 + tid;
  int m = g >> 21;
  int n = g & (NTOT-1);
  int c = (n >> 14) & 63;
  size_t idx = (size_t)g;
  int best = din[idx];
  #pragma unroll 4
  for (int k=1; k<=16; ++k){
    if (best <= k) break;
    int v = 255;
    if (c-k >= 0)  v = din[idx - (size_t)k*16384];
    if (c+k < 64)  v = min(v, (int)din[idx + (size_t)k*16384]);
    best = min(best, max(k, v));
  }
  dout[idx] = (u8)best;
  int wi = n>>6, bit = n&63;
  u64 sbit = m ? (skel2[NWORDS+wi] & hbits[wi]) : skel2[wi];
  u32 r = (u32)((sbit>>bit)&1ull) ? (u32)best : 0u;
  __shared__ u32 sx[256], sn_[256];
  sx[tid]=r; sn_[tid]=r;
  __syncthreads();
  for(int s=128;s>0;s>>=1){
    if(tid<s){
      if(sx[tid+s]>sx[tid]) sx[tid]=sx[tid+s];
      if(sn_[tid+s]<sn_[tid]) sn_[tid]=sn_[tid+s];
    }
    __syncthreads();
  }
  if(tid==0){ pmaxv[blockIdx.x]=(u8)sx[0]; pminv[blockIdx.x]=(u8)sn_[0]; }
}

// reduce 16384 block partials -> mm[8]
__global__ __launch_bounds__(256) void rmm2(const u8* __restrict__ pmaxv, const u8* __restrict__ pminv,
                                            u32* __restrict__ mm){
  __shared__ u8 smx[4][256], smn[4][256];
  int tid = threadIdx.x;
  u8 mx[4]={0,0,0,0}, mn[4]={255,255,255,255};
  for(int i=tid;i<16384;i+=256){
    int sel=i>>13, b=(i>>12)&1, cc=sel*2+b;
    u8 a=pmaxv[i], d=pminv[i];
    if(a>mx[cc]) mx[cc]=a;
    if(d<mn[cc]) mn[cc]=d;
  }
  #pragma unroll
  for(int cc=0;cc<4;cc++){ smx[cc][tid]=mx[cc]; smn[cc][tid]=mn[cc]; }
  __syncthreads();
  for(int s=128;s>0;s>>=1){
    if(tid<s){
      #pragma unroll
      for(int cc=0;cc<4;cc++){
        if(smx[cc][tid+s]>smx[cc][tid]) smx[cc][tid]=smx[cc][tid+s];
        if(smn[cc][tid+s]<smn[cc][tid]) smn[cc][tid]=smn[cc][tid+s];
      }
    }
    __syncthreads();
  }
  if(tid==0){
    #pragma unroll
    for(int cc=0;cc<4;cc++){
      int sel=cc>>1, b=cc&1;
      mm[sel*4+b]   = (u32)smx[cc][0];
      mm[sel*4+2+b] = (u32)smn[cc][0];
    }
  }
}

// ---------------- k_tail: LDS-tiled separable sobel + final reduce (float partials) --------
__global__ __launch_bounds__(256) void k_tail(const float* __restrict__ net, const u16* __restrict__ prob,
    const u16* __restrict__ skelp, const u64* __restrict__ ybits, const u64* __restrict__ hbits,
    const u64* __restrict__ skel2, const u8* __restrict__ acc, const u32* __restrict__ mm,
    double* __restrict__ part1)
{
  __shared__ float lp[2040];
  __shared__ float dxp[1920];
  __shared__ float sxp[1920];
  __shared__ char  dxt8[1920];
  __shared__ u8    sxt8[1920];
  __shared__ u64   wrow[60];
  __shared__ double sw[9][4];
  int tid = threadIdx.x;
  int bid = blockIdx.x;
  int xb = bid&3, ybk=(bid>>2)&15, zbk=(bid>>6)&15, b=bid>>10;
  int X0=xb*32, Y0=ybk*8, Z0=zbk*4;
  const float* P = net + (size_t)b*(2*VOL);
  float rmaxT = fmaxf((float)mm[b],1.f),   rminT = fmaxf((float)mm[2+b],1.f);
  float rmaxH = fmaxf((float)mm[4+b],1.f), rminH = fmaxf((float)mm[6+b],1.f);
  for (int idx=tid; idx<2040; idx+=256){
    int zr = idx/340; int rem = idx-zr*340; int yr = rem/34; int xi = rem-yr*34;
    int gz=Z0-1+zr, gy=Y0-1+yr, gx=X0-1+xi;
    float v = 0.f;
    if((unsigned)gz<64u && (unsigned)gy<128u && (unsigned)gx<128u)
      v = P[(gz<<14)+(gy<<7)+gx];
    lp[idx] = v;
  }
  if (tid < 60){
    int zr = tid/10, yr = tid-zr*10;
    int gz=Z0-1+zr, gy=Y0-1+yr;
    u64 wn = 0;
    if((unsigned)gz<64u && (unsigned)gy<128u){
      const u64* yw = ybits + ((size_t)b<<14) + (gz<<8) + (gy<<1);
      u64 w0 = yw[0], w1 = yw[1];
      if (X0==0) wn = w0<<1;
      else { int s = X0-1; wn = (s<64) ? ((w0>>s)|(w1<<(64-s))) : (w1>>(s-64)); }
    }
    wrow[tid] = wn;
  }
  __syncthreads();
  for (int idx=tid; idx<1920; idx+=256){
    int zr = idx/320; int rem = idx-zr*320; int yr = rem>>5; int x = rem&31;
    int c = zr*340 + yr*34 + x;
    float l0=lp[c], l1=lp[c+1], l2=lp[c+2];
    dxp[idx] = l2-l0;
    sxp[idx] = l0+2.f*l1+l2;
    u64 wn = wrow[zr*10+yr];
    int bm=(int)((wn>>x)&1ull), b1=(int)((wn>>(x+1))&1ull), bp=(int)((wn>>(x+2))&1ull);
    dxt8[idx] = (char)(bp-bm);
    sxt8[idx] = (u8)(bm+2*b1+bp);
  }
  __syncthreads();
  int oy = tid>>5, ox = tid&31;
  float A1[6],A2[6],A3[6];
  int   B1v[6],B2v[6],B3v[6];
  #pragma unroll
  for(int zr=0; zr<6; ++zr){
    int base = zr*320 + oy*32 + ox;
    float d0=dxp[base], d1=dxp[base+32], d2=dxp[base+64];
    A1[zr] = d0+2.f*d1+d2;
    A2[zr] = d0+d1+d2;
    float s0=sxp[base], s1=sxp[base+32], s2=sxp[base+64];
    A3[zr] = s0+s1+s2;
    int t0=dxt8[base], t1=dxt8[base+32], t2=dxt8[base+64];
    B1v[zr] = t0+2*t1+t2;
    B2v[zr] = t0+t1+t2;
    int u0=sxt8[base], u1=sxt8[base+32], u2=sxt8[base+64];
    B3v[zr] = u0+u1+u2;
  }
  float fsob=0,cl1=0,cl2=0,cl3=0,cl4=0,i1=0,un1=0,i2=0,un2=0;
  #pragma unroll
  for(int zc=0; zc<4; ++zc){
    float gpx = A1[zc]+A1[zc+1]+A1[zc+2];
    float gpy = A2[zc]+2.f*A2[zc+1]+A2[zc+2];
    float gpz = A3[zc+2]-A3[zc];
    float ftx = (float)(B1v[zc]+B1v[zc+1]+B1v[zc+2]);
    float fty = (float)(B2v[zc]+2*B2v[zc+1]+B2v[zc+2]);
    float ftz = (float)(B3v[zc+2]-B3v[zc]);
    float s1 = gpx*gpx+gpy*gpy+gpz*gpz;
    float s2 = ftx*ftx+fty*fty+ftz*ftz;
    if (s1>0.f && s2>0.f){
      float ip = rsqrtf(s1), it = rsqrtf(s2);
      fsob += (gpx*ftx+gpy*fty+gpz*ftz)*ip*it;
    }
    int gz=Z0+zc, gy=Y0+oy, gx=X0+ox;
    int n = (b<<20)+(gz<<14)+(gy<<7)+gx;
    int yb = (int)((wrow[(zc+1)*10+(oy+1)] >> (ox+1)) & 1ull);
    int wi = n>>6, bit = n&63;
    int hd = (int)((hbits[wi]>>bit)&1ull);
    int sT = (int)((skel2[wi]>>bit)&1ull);
    int sH = (int)((skel2[NWORDS+wi]>>bit)&1ull);
    float dT = (float)acc[n];
    float dH = (float)acc[(size_t)NTOT+n];
    float p  = h2f(prob[n]);
    float sk = h2f(skelp[n]);
    cl1 += sk*(float)yb;
    cl2 += sk;
    float q_vl = yb ? fminf(dT,rmaxT)/rmaxT : 0.f;
    if (sT){
      cl3 += p; cl4 += 1.f;
      float t=(rmaxT-dT+rminT)/rmaxT; float q_sl=t*t;
      float q_vp = fminf(dH,rmaxH)/rmaxH*p;
      i2  += q_sl*__powf(q_vp+1e-4f,0.7f)*q_sl;
      un2 += q_sl*(0.1f*q_vp+0.9f*q_sl);
    }
    if (sH & hd){
      float t=(rmaxH-dH+rminH)/rmaxH; float q_sp=t*t*p;
      i1  += q_sp*__powf(q_sp+1e-4f,0.7f)*q_vl;
      un1 += q_sp*(0.1f*q_sp+0.9f*q_vl);
    }
  }
  int wid = tid>>6, lane = tid&63;
  double vals[9] = {(double)fsob,(double)cl1,(double)cl2,(double)cl3,(double)cl4,
                    (double)i1,(double)un1,(double)i2,(double)un2};
  #pragma unroll
  for(int s=0;s<9;s++){ double rr = wred(vals[s]); if(lane==0) sw[s][wid]=rr; }
  __syncthreads();
  if(tid==0){
    #pragma unroll
    for(int s=0;s<9;s++) part1[(size_t)s*PC1 + bid] = sw[s][0]+sw[s][1]+sw[s][2]+sw[s][3];
  }
}

// ---------------- two-stage finalize ----------------
__global__ __launch_bounds__(256) void k_reduce_mid(const double* __restrict__ part0,
                                                    const double* __restrict__ part1,
                                                    double* __restrict__ tot){
  int s = blockIdx.x;
  const double* src; int n;
  if (s < 5){ src = part0 + (size_t)s*PC0; n = PC0; }
  else      { src = part1 + (size_t)(s-5)*PC1; n = PC1; }
  double v=0;
  for(int i=threadIdx.x;i<n;i+=256) v += src[i];
  __shared__ double sd[256];
  sd[threadIdx.x]=v; __syncthreads();
  for(int k=128;k>0;k>>=1){ if((int)threadIdx.x<k) sd[threadIdx.x]+=sd[threadIdx.x+k]; __syncthreads(); }
  if(threadIdx.x==0) tot[s]=sd[0];
}

__global__ void k_fin(const double* __restrict__ tot, float* __restrict__ out){
  if(threadIdx.x==0 && blockIdx.x==0){
    const double N = (double)NTOT;
    double ce = tot[0]/N;
    double tp=tot[1], fp=tot[2]-tot[1], fn=tot[3]-tot[1];
    double dice = -((2.0*tp+1e-5)/(2.0*tp+fp+fn+1e-5));
    double conn = tot[4]/(2.0*N);
    double dir  = 1.0 - tot[5]/N;
    double tprec = (tot[6]+1.0)/(tot[7]+1.0);
    double tsens = (tot[8]+1.0)/(tot[9]+1.0);
    double cld = 1.0 - 2.0*tprec*tsens/(tprec+tsens);
    double u1 = 1.0 - (tot[10]+1.0)/(tot[11]+1.0);
    double u2 = 1.0 - (tot[12]+1.0)/(tot[13]+1.0);
    out[0] = (float)(dice+ce+cld+dir+conn+u1+u2);
  }
}

extern "C" void kernel_launch(void* const* d_in, const int* in_sizes, int n_in,
                              void* d_out, int out_size, void* d_ws, size_t ws_size,
                              hipStream_t stream)
{
  (void)in_sizes; (void)n_in; (void)out_size; (void)ws_size;
  const float* net = (const float*)d_in[0];
  const int*   tgt = (const int*)d_in[1];
  float* out = (float*)d_out;
  char* w = (char*)d_ws;
  const size_t MB = 1024*1024;
  u16* F1 = (u16*)(w + 0*MB);              // prob img ping (fp16)
  u16* F2 = (u16*)(w + 4*MB);              // skel_pred
  u16* F3 = (u16*)(w + 8*MB);              // img pong
  u16* F4 = (u16*)(w + 12*MB);             // pristine prob copy
  u64* ybits = (u64*)(w + 16*MB);
  u64* hbits = ybits + NWORDS;
  u64* skel2 = hbits + NWORDS;
  u64* bping = skel2 + 2*NWORDS;
  u64* bpong = bping + 2*NWORDS;
  u8*  dA    = (u8*)(bpong + 2*NWORDS);
  u8*  dB    = dA + (size_t)2*NTOT;
  double* part0 = (double*)(dB + (size_t)2*NTOT);
  double* part1 = part0 + (size_t)5*PC0;
  double* tot   = part1 + (size_t)9*PC1;
  u8* pmaxv = (u8*)(tot + 16);
  u8* pminv = pmaxv + 16384;
  u32* mm  = (u32*)(pminv + 16384);

  k_init<<<PC0, 256, 0, stream>>>(net, tgt, F1, F4, ybits, hbits, bping, dA, part0);

  // binary skeleton: INIT + 4 false iterations standalone
  bskel<true><<<128,256,0,stream>>>(bping, bpong, skel2);
  bskel<false><<<128,256,0,stream>>>(bping, bpong, skel2);
  bskel<false><<<128,256,0,stream>>>(bpong, bping, skel2);
  bskel<false><<<128,256,0,stream>>>(bping, bpong, skel2);
  bskel<false><<<128,256,0,stream>>>(bpong, bping, skel2);

  // fskel chain with bskel #5..#10 piggybacked; #1 also carries edt_py (extra 2048 blocks)
  fsk_b<0><<<3200,512,0,stream>>>(F1, F3, F2, bping, bpong, skel2, dA, dB);
  fsk_b<1><<<1152,512,0,stream>>>(F3, F1, F2, bpong, bping, skel2, dA, dB);
  fsk_b<1><<<1152,512,0,stream>>>(F1, F3, F2, bping, bpong, skel2, dA, dB);
  fsk_b<1><<<1152,512,0,stream>>>(F3, F1, F2, bpong, bping, skel2, dA, dB);
  fsk_b<1><<<1152,512,0,stream>>>(F1, F3, F2, bping, bpong, skel2, dA, dB);
  fsk_b<2><<<1152,512,0,stream>>>(F3, F1, F2, bpong, bping, skel2, dA, dB);

  const int GE = (2*NTOT)/256;
  edt_pz_part<<<GE,256,0,stream>>>(dB, dA, skel2, hbits, pmaxv, pminv);
  rmm2<<<1,256,0,stream>>>(pmaxv, pminv, mm);

  k_tail<<<PC1,256,0,stream>>>(net, F4, F2, ybits, hbits, skel2, dA, mm, part1);
  k_reduce_mid<<<14,256,0,stream>>>(part0, part1, tot);
  k_fin<<<1,64,0,stream>>>(tot, out);
}